// Round 7
// baseline (153.806 us; speedup 1.0000x reference)
//
#include <hip/hip_runtime.h>
#include <hip/hip_bf16.h>
#include <cstdint>

// Problem constants (reference: B=4, K=32, S=1024, H=512, FFN=2304)
#define BB 4
#define KK 32
#define SS 1024
#define HH 512
#define FFN 2304
#define M_PAIRS (BB * KK * KK)   // 4096
#define K1 (3 * HH)              // 1536

using bf16 = __hip_bfloat16;
using f32x4 = __attribute__((ext_vector_type(4))) float;
using bf16x8 = __attribute__((ext_vector_type(8))) short;

struct bf16x2 { bf16 x, y; };

__device__ __forceinline__ float bf2f(bf16 v) { return __bfloat162float(v); }

// ---------------------------------------------------------------------------
// Transpose + f32->bf16 cast: in[R][C] f32 -> out[C][R] bf16. 32x32 tiles.
// ---------------------------------------------------------------------------
__global__ __launch_bounds__(256) void transpose_to_bf16(
    const float* __restrict__ in, bf16* __restrict__ out, int R, int C)
{
    __shared__ float tile[32][33];
    int bc = blockIdx.x * 32;
    int br = blockIdx.y * 32;
    int tx = threadIdx.x & 31;
    int ty = threadIdx.x >> 5;
#pragma unroll
    for (int i = 0; i < 32; i += 8)
        tile[ty + i][tx] = in[(size_t)(br + ty + i) * C + bc + tx];
    __syncthreads();
#pragma unroll
    for (int i = 0; i < 32; i += 8)
        out[(size_t)(bc + ty + i) * R + br + tx] = __float2bfloat16(tile[tx][ty + i]);
}

// ---------------------------------------------------------------------------
// Sparse range-max table, every-other level: window sizes q = 4,16,64,256.
// ---------------------------------------------------------------------------
#define TBL_LVL_STRIDE ((size_t)BB * SS * HH)

__global__ __launch_bounds__(256) void build_table_l0(
    const float* __restrict__ tok, bf16* __restrict__ tbl0)
{
    int bt = blockIdx.x;
    int b = bt >> 10, t = bt & 1023;
    int h0 = threadIdx.x * 2;
    const float* base = tok + (size_t)b * SS * HH;
    float m0 = -INFINITY, m1 = -INFINITY;
#pragma unroll
    for (int j = 0; j < 4; ++j) {
        int tt = min(t + j, SS - 1);
        float2 v = *(const float2*)(base + (size_t)tt * HH + h0);
        m0 = fmaxf(m0, v.x);
        m1 = fmaxf(m1, v.y);
    }
    bf16x2 o;
    o.x = __float2bfloat16(m0);
    o.y = __float2bfloat16(m1);
    *(bf16x2*)(tbl0 + (size_t)bt * HH + h0) = o;
}

__global__ __launch_bounds__(256) void build_table_next(
    const bf16* __restrict__ prev, bf16* __restrict__ out, int qp)
{
    int bt = blockIdx.x;
    int b = bt >> 10, t = bt & 1023;
    int h0 = threadIdx.x * 2;
    const bf16* base = prev + (size_t)b * SS * HH;
    float m0 = -INFINITY, m1 = -INFINITY;
#pragma unroll
    for (int j = 0; j < 4; ++j) {
        int tt = min(t + j * qp, SS - qp);
        bf16x2 v = *(const bf16x2*)(base + (size_t)tt * HH + h0);
        m0 = fmaxf(m0, bf2f(v.x));
        m1 = fmaxf(m1, bf2f(v.y));
    }
    bf16x2 o;
    o.x = __float2bfloat16(m0);
    o.y = __float2bfloat16(m1);
    *(bf16x2*)(out + (size_t)bt * HH + h0) = o;
}

// ---------------------------------------------------------------------------
// build_rel: one block per pair (b,i,j). Vectorized 2-elem per thread.
// ---------------------------------------------------------------------------
__global__ __launch_bounds__(256) void build_rel(
    const float* __restrict__ cand,
    const float* __restrict__ tok,
    const int* __restrict__ ids,
    const bf16* __restrict__ tbl,
    bf16* __restrict__ rel)
{
    int pair = blockIdx.x;
    int b = pair >> 10;
    int i = (pair >> 5) & 31;
    int j = pair & 31;
    int h2 = threadIdx.x * 2;           // 0,2,..,510

    int si = ids[((b * KK + i) << 1)];
    int ei = ids[((b * KK + i) << 1) + 1];
    int sj = ids[((b * KK + j) << 1)];
    int ej = ids[((b * KK + j) << 1) + 1];
    int me = min(ei, ej);
    int ms = max(si, sj);

    const float* head = cand + ((size_t)b * KK + i) * HH;
    const float* tail = cand + ((size_t)b * KK + j) * HH;
    bf16* outp = rel + (size_t)pair * K1;

    float2 hv = *(const float2*)(head + h2);
    float2 tv = *(const float2*)(tail + h2);
    bf16x2 o;
    o.x = __float2bfloat16(hv.x); o.y = __float2bfloat16(hv.y);
    *(bf16x2*)(outp + h2) = o;
    o.x = __float2bfloat16(tv.x); o.y = __float2bfloat16(tv.y);
    *(bf16x2*)(outp + HH + h2) = o;

    bf16* ctx = outp + 2 * HH;
    if (me < ms) {
        int L = ms - me;
        float m0 = -INFINITY, m1 = -INFINITY;
        if (L < 4) {
            const float* tb = tok + (size_t)b * SS * HH;
            for (int tt = me; tt < ms; ++tt) {
                float2 v = *(const float2*)(tb + (size_t)tt * HH + h2);
                m0 = fmaxf(m0, v.x);
                m1 = fmaxf(m1, v.y);
            }
        } else {
            int lvl = (L < 16) ? 0 : (L < 64) ? 1 : (L < 256) ? 2 : 3;
            int q = 4 << (2 * lvl);
            const bf16* base = tbl + (size_t)lvl * TBL_LVL_STRIDE + (size_t)b * SS * HH;
#pragma unroll
            for (int jj = 0; jj < 4; ++jj) {
                int p = min(me + jj * q, ms - q);
                bf16x2 v = *(const bf16x2*)(base + (size_t)p * HH + h2);
                m0 = fmaxf(m0, bf2f(v.x));
                m1 = fmaxf(m1, bf2f(v.y));
            }
        }
        o.x = __float2bfloat16(m0);
        o.y = __float2bfloat16(m1);
        *(bf16x2*)(ctx + h2) = o;
    } else {
        o.x = __float2bfloat16(hv.x);
        o.y = __float2bfloat16(hv.y);
        *(bf16x2*)(ctx + h2) = o;
    }
}

// ---------------------------------------------------------------------------
__device__ __forceinline__ void gload_lds16(const bf16* g, bf16* l)
{
    __builtin_amdgcn_global_load_lds(
        (const __attribute__((address_space(1))) unsigned int*)g,
        (__attribute__((address_space(3))) unsigned int*)l,
        16, 0, 0);
}

#define BAR() asm volatile("s_barrier" ::: "memory")
#define VMCNT0() asm volatile("s_waitcnt vmcnt(0)" ::: "memory")

// ---------------------------------------------------------------------------
// gemm_adirect: A-DIRECT GEMM, 4 waves (256 thr) in 2Mx2N grid.
// Block = (2*MF*16) x (2*NF*16); wave tile = (MF*16) x (NF*16).
// A-fragments load straight from global (L2/L3-resident) into registers,
// double-buffered one K-tile ahead; only B flows through LDS (32 KB dbuf,
// verified 16B-chunk XOR swizzle both-sides). 2 blocks/CU co-residency
// (8 waves/CU) hides the per-tile vmcnt(0) drain (m114) -- this is the fix
// for round-6's 1-wave/SIMD latency exposure.
// MODE 0: GEMM1 grid 576 (32bm x 18bn), 2-D XCD chunks (8 x [8bm x 9bn]).
// MODE 1: linear chunked XCD swizzle + split-K via nper.
// ---------------------------------------------------------------------------
template <int MF, int NF, bool RELU, bool OUT_BF16, bool ADD_BIAS, int MODE>
__global__ __launch_bounds__(256, 2) void gemm_adirect(
    const bf16* __restrict__ A,    // [M_PAIRS][lda]
    const bf16* __restrict__ BT,   // [*][ldb]
    const float* __restrict__ bias,
    void* __restrict__ Cout,       // [M_PAIRS][ldc] per split
    int lda, int ldb, int NT, int nbn, int nper, int ldc)
{
    constexpr int BN_ = 2 * NF * 16;
    constexpr int BM_ = 2 * MF * 16;
    __shared__ __align__(16) bf16 ldsB[2][BN_ * 64];

    int bm, bn, s;
    if (MODE == 0) {   // 8 XCD chunks of 8bm x 9bn (grid 576)
        int x = blockIdx.x & 7, k = blockIdx.x >> 3;   // k in 0..71
        bm = (x & 3) * 8 + (k & 7);                    // 0..31
        bn = (x >> 2) * 9 + (k >> 3);                  // 0..17
        s = 0;
    } else {
        int cpx = gridDim.x >> 3;
        int wg = (blockIdx.x & 7) * cpx + (blockIdx.x >> 3);
        s = wg / nper;
        int rem = wg - s * nper;
        bm = rem / nbn;
        bn = rem - bm * nbn;
    }
    const int row0 = bm * BM_;
    const int col0 = bn * BN_;

    const bf16* As = A  + (size_t)s * NT * 64;   // K-split offset
    const bf16* Bs = BT + (size_t)s * NT * 64;

    const int tid = threadIdx.x;
    const int w = tid >> 6, l = tid & 63;
    const int wm = w >> 1;          // 0..1 -> rows wm*(MF*16)
    const int wn = w & 1;           // 0..1 -> cols wn*(NF*16)

    // staging lane constants (pre-swizzled source chunk; linear LDS dest)
    const int lr  = l >> 3;                      // 0..7
    const int lch = (l & 7) ^ lr;
    // ds_read swizzled offsets (read row&7 == l&7)
    const int l15 = l & 15;
    const int sw0 = (((l >> 4)    ) ^ (l & 7)) * 16;
    const int sw1 = (((l >> 4) + 4) ^ (l & 7)) * 16;

    auto stageB = [&](int t, int sb) {
        const bf16* g = Bs + (size_t)(col0 + w * (BN_ / 4) + lr) * ldb + t * 64 + lch * 8;
        bf16* d = &ldsB[sb][(w * (BN_ / 4)) * 64];
#pragma unroll
        for (int j = 0; j < BN_ / 32; ++j)
            gload_lds16(g + (size_t)(j * 8) * ldb, d + j * 512);
    };

    // A-fragment direct load: lane l -> row m*16+(l&15), k-chunk (l>>4)*8.
    auto loadA = [&](bf16x8 (&af)[MF][2], int t) {
#pragma unroll
        for (int m = 0; m < MF; ++m) {
            const bf16* p = As + (size_t)(row0 + wm * (MF * 16) + m * 16 + l15) * lda
                            + t * 64 + (l >> 4) * 8;
            af[m][0] = *(const bf16x8*)p;
            af[m][1] = *(const bf16x8*)(p + 32);
        }
    };

    f32x4 acc[MF][NF] = {};

    auto comp = [&](bf16x8 (&af)[MF][2], int sb) {
        const char* Bb = (const char*)&ldsB[sb][0] + (wn * (NF * 16) + l15) * 128;
        bf16x8 bfr[NF][2];
#pragma unroll
        for (int n = 0; n < NF; ++n) {
            const char* p = Bb + n * 2048;
            bfr[n][0] = *(const bf16x8*)(p + sw0);
            bfr[n][1] = *(const bf16x8*)(p + sw1);
        }
        __builtin_amdgcn_s_setprio(1);
#pragma unroll
        for (int m = 0; m < MF; ++m)
#pragma unroll
            for (int n = 0; n < NF; ++n)
#pragma unroll
                for (int kk = 0; kk < 2; ++kk)
                    acc[m][n] = __builtin_amdgcn_mfma_f32_16x16x32_bf16(
                        af[m][kk], bfr[n][kk], acc[m][n], 0, 0, 0);
        __builtin_amdgcn_s_setprio(0);
    };

    bf16x8 afA[MF][2], afB[MF][2];

    loadA(afA, 0);
    stageB(0, 0);
    VMCNT0();
    BAR();

    for (int t = 0; t < NT; t += 2) {           // NT even (24 / 18)
        stageB(t + 1, 1);
        loadA(afB, t + 1);
        comp(afA, 0);
        VMCNT0();
        BAR();
        if (t + 2 < NT) { stageB(t + 2, 0); loadA(afA, t + 2); }
        comp(afB, 1);
        VMCNT0();
        BAR();
    }

    // epilogue. C/D: col=lane&15, row=(lane>>4)*4+q
    const int crow = (l >> 4) * 4;
    char* outBase = (char*)Cout + (size_t)s * M_PAIRS * ldc * (OUT_BF16 ? 2 : 4);
#pragma unroll
    for (int m = 0; m < MF; ++m) {
        int row = row0 + wm * (MF * 16) + m * 16 + crow;
#pragma unroll
        for (int n = 0; n < NF; ++n) {
            int col = col0 + wn * (NF * 16) + n * 16 + l15;
            float bv = ADD_BIAS ? bias[col] : 0.f;
#pragma unroll
            for (int q = 0; q < 4; ++q) {
                float v = acc[m][n][q] + bv;
                if (RELU) v = fmaxf(v, 0.f);
                size_t idx = (size_t)(row + q) * ldc + col;
                if (OUT_BF16)
                    ((bf16*)outBase)[idx] = __float2bfloat16(v);
                else
                    ((float*)outBase)[idx] = v;
            }
        }
    }
}

// ---------------------------------------------------------------------------
// reduce: out = P0 + P1 + bias  (f32, vectorized float4)
// ---------------------------------------------------------------------------
__global__ __launch_bounds__(256) void reduce_bias(
    const float* __restrict__ P, const float* __restrict__ b2,
    float* __restrict__ out)
{
    int idx = blockIdx.x * 256 + threadIdx.x;        // float4 index
    const float4* p0 = (const float4*)P;
    const float4* p1 = (const float4*)(P + (size_t)M_PAIRS * HH);
    float4 a = p0[idx];
    float4 b = p1[idx];
    float4 bv = ((const float4*)b2)[idx & 127];      // 512 cols = 128 float4
    float4 r;
    r.x = a.x + b.x + bv.x;
    r.y = a.y + b.y + bv.y;
    r.z = a.z + b.z + bv.z;
    r.w = a.w + b.w + bv.w;
    ((float4*)out)[idx] = r;
}

// ---------------------------------------------------------------------------
extern "C" void kernel_launch(void* const* d_in, const int* in_sizes, int n_in,
                              void* d_out, int out_size, void* d_ws, size_t ws_size,
                              hipStream_t stream)
{
    const float* cand = (const float*)d_in[0];
    const float* tok  = (const float*)d_in[1];
    const float* W1   = (const float*)d_in[2];
    const float* b1   = (const float*)d_in[3];
    const float* W2   = (const float*)d_in[4];
    const float* b2   = (const float*)d_in[5];
    const int*   ids  = (const int*)d_in[6];
    float* out = (float*)d_out;

    char* ws = (char*)d_ws;
    const size_t relB_sz = (size_t)M_PAIRS * K1 * 2;        // 12,582,912
    const size_t w1t_sz  = (size_t)FFN * K1 * 2;            //  7,077,888
    const size_t w2t_sz  = (size_t)HH * FFN * 2;            //  2,359,296
    bf16* relB = (bf16*)ws;
    bf16* W1T  = (bf16*)(ws + relB_sz);
    bf16* W2T  = (bf16*)(ws + relB_sz + w1t_sz);
    char* regionX = ws + relB_sz + w1t_sz + w2t_sz;
    bf16* tbl = (bf16*)regionX;   // 16 MB, dead after build_rel
    bf16* hid = (bf16*)regionX;   // 18.9 MB, written by GEMM1 afterwards
    // GEMM2 split-K partials: 2 x 4096 x 512 f32 = 16.78 MB, aliases
    // relB (12.6 MB) + W1T (7.1 MB) -- both dead after GEMM1. W2T/hid live.
    float* P = (float*)ws;

    // 1) weight transpose+cast
    transpose_to_bf16<<<dim3(FFN / 32, K1 / 32), 256, 0, stream>>>(W1, W1T, K1, FFN);
    transpose_to_bf16<<<dim3(HH / 32, FFN / 32), 256, 0, stream>>>(W2, W2T, FFN, HH);

    // 2) sparse range-max table: q = 4, 16, 64, 256
    build_table_l0<<<BB * SS, 256, 0, stream>>>(tok, tbl);
    build_table_next<<<BB * SS, 256, 0, stream>>>(tbl + 0 * TBL_LVL_STRIDE,
                                                  tbl + 1 * TBL_LVL_STRIDE, 4);
    build_table_next<<<BB * SS, 256, 0, stream>>>(tbl + 1 * TBL_LVL_STRIDE,
                                                  tbl + 2 * TBL_LVL_STRIDE, 16);
    build_table_next<<<BB * SS, 256, 0, stream>>>(tbl + 2 * TBL_LVL_STRIDE,
                                                  tbl + 3 * TBL_LVL_STRIDE, 64);

    // 3) build rel = [heads|tails|context] bf16
    build_rel<<<M_PAIRS, 256, 0, stream>>>(cand, tok, ids, tbl, relB);

    // 4) hid = relu(rel @ W1 + b1) -> bf16. A-direct, block 128x128, 4 waves,
    //    grid 32x18 = 576, 2 blocks/CU co-resident, 2-D XCD chunks.
    gemm_adirect<4, 4, true, true, true, 0><<<576, 256, 0, stream>>>(
        relB, W1T, b1, hid, K1, K1, /*NT=*/24, /*nbn=*/18, /*nper=*/576, FFN);

    // 5) P[s] = hid @ W2 (K-split 2, no bias) -> f32. A-direct, block 64x128,
    //    grid 2 x (64x4) = 512 = 2 blocks/CU.
    gemm_adirect<2, 4, false, false, false, 1><<<512, 256, 0, stream>>>(
        hid, W2T, nullptr, P, FFN, FFN, /*NT=*/18, /*nbn=*/4, /*nper=*/256, HH);

    // 6) out = P0 + P1 + b2
    reduce_bias<<<(M_PAIRS * HH / 4) / 256, 256, 0, stream>>>(P, b2, out);
}

// Round 8
// 98.005 us; speedup vs baseline: 1.5694x; 1.5694x over previous
//
#include <hip/hip_runtime.h>
#include <hip/hip_bf16.h>
#include <cstdint>

// Problem constants (reference: B=4, K=32, S=1024, H=512, FFN=2304)
#define BB 4
#define KK 32
#define SS 1024
#define HH 512
#define FFN 2304
#define M_PAIRS (BB * KK * KK)   // 4096
#define K1 (3 * HH)              // 1536

using bf16 = __hip_bfloat16;
using f32x4 = __attribute__((ext_vector_type(4))) float;
using bf16x8 = __attribute__((ext_vector_type(8))) short;

struct bf16x2 { bf16 x, y; };

__device__ __forceinline__ float bf2f(bf16 v) { return __bfloat162float(v); }

// ---------------------------------------------------------------------------
// Fused weight transposes: W1[1536][2304] -> W1T[2304][1536] and
// W2[2304][512] -> W2T[512][2304], one kernel (saves a launch).
// ---------------------------------------------------------------------------
#define W1_TILES (72 * 48)     // (2304/32) x (1536/32)
#define W2_TILES (16 * 72)     // (512/32)  x (2304/32)

__global__ __launch_bounds__(256) void transpose_both(
    const float* __restrict__ W1, bf16* __restrict__ W1T,
    const float* __restrict__ W2, bf16* __restrict__ W2T)
{
    __shared__ float tile[32][33];
    const float* in; bf16* out; int R, C, bx, by;
    int bid = blockIdx.x;
    if (bid < W1_TILES) {
        in = W1; out = W1T; R = K1; C = FFN;
        bx = bid % 72; by = bid / 72;
    } else {
        bid -= W1_TILES;
        in = W2; out = W2T; R = FFN; C = HH;
        bx = bid % 16; by = bid / 16;
    }
    int bc = bx * 32, br = by * 32;
    int tx = threadIdx.x & 31;
    int ty = threadIdx.x >> 5;
#pragma unroll
    for (int i = 0; i < 32; i += 8)
        tile[ty + i][tx] = in[(size_t)(br + ty + i) * C + bc + tx];
    __syncthreads();
#pragma unroll
    for (int i = 0; i < 32; i += 8)
        out[(size_t)(bc + ty + i) * R + br + tx] = __float2bfloat16(tile[tx][ty + i]);
}

// ---------------------------------------------------------------------------
// Sparse range-max tables, window sizes q = 4,16,64,256, bf16.
// Fused: tableA builds l0(q=4)+l1(q=16) from f32 tok; tableB builds
// l2(q=64)+l3(q=256) from l1. In-range entries (t <= S-q, the only ones
// queried: p <= ms-q <= S-q) are exact window maxima == the 4-level
// hierarchical build. bf16 rounding is monotone -> max(round)==round(max).
// XCD-contiguous t-chunks: bt = (bid&7)*512 + (bid>>3).
// ---------------------------------------------------------------------------
#define TBL_LVL_STRIDE ((size_t)BB * SS * HH)

__global__ __launch_bounds__(256) void build_table_A(
    const float* __restrict__ tok, bf16* __restrict__ tbl0,
    bf16* __restrict__ tbl1)
{
    int bt = ((blockIdx.x & 7) << 9) + (blockIdx.x >> 3);
    int b = bt >> 10, t = bt & 1023;
    int h0 = threadIdx.x * 2;
    const float* base = tok + (size_t)b * SS * HH;
    float m0 = -INFINITY, m1 = -INFINITY;
    float l00 = 0.f, l01 = 0.f;
#pragma unroll
    for (int j = 0; j < 16; ++j) {
        int tt = min(t + j, SS - 1);
        float2 v = *(const float2*)(base + (size_t)tt * HH + h0);
        m0 = fmaxf(m0, v.x);
        m1 = fmaxf(m1, v.y);
        if (j == 3) { l00 = m0; l01 = m1; }
    }
    bf16x2 o;
    o.x = __float2bfloat16(l00);
    o.y = __float2bfloat16(l01);
    *(bf16x2*)(tbl0 + (size_t)bt * HH + h0) = o;
    o.x = __float2bfloat16(m0);
    o.y = __float2bfloat16(m1);
    *(bf16x2*)(tbl1 + (size_t)bt * HH + h0) = o;
}

__global__ __launch_bounds__(256) void build_table_B(
    const bf16* __restrict__ tbl1, bf16* __restrict__ tbl2,
    bf16* __restrict__ tbl3)
{
    int bt = ((blockIdx.x & 7) << 9) + (blockIdx.x >> 3);
    int b = bt >> 10, t = bt & 1023;
    int h0 = threadIdx.x * 2;
    const bf16* base = tbl1 + (size_t)b * SS * HH;
    float m0 = -INFINITY, m1 = -INFINITY;
    float l20 = 0.f, l21 = 0.f;
#pragma unroll
    for (int j = 0; j < 16; ++j) {
        int tt = min(t + j * 16, SS - 16);
        bf16x2 v = *(const bf16x2*)(base + (size_t)tt * HH + h0);
        m0 = fmaxf(m0, bf2f(v.x));
        m1 = fmaxf(m1, bf2f(v.y));
        if (j == 3) { l20 = m0; l21 = m1; }
    }
    bf16x2 o;
    o.x = __float2bfloat16(l20);
    o.y = __float2bfloat16(l21);
    *(bf16x2*)(tbl2 + (size_t)bt * HH + h0) = o;
    o.x = __float2bfloat16(m0);
    o.y = __float2bfloat16(m1);
    *(bf16x2*)(tbl3 + (size_t)bt * HH + h0) = o;
}

// ---------------------------------------------------------------------------
// build_rel: one block per pair (b,i,j). Vectorized 2-elem per thread.
// ---------------------------------------------------------------------------
__global__ __launch_bounds__(256) void build_rel(
    const float* __restrict__ cand,
    const float* __restrict__ tok,
    const int* __restrict__ ids,
    const bf16* __restrict__ tbl,
    bf16* __restrict__ rel)
{
    int pair = blockIdx.x;
    int b = pair >> 10;
    int i = (pair >> 5) & 31;
    int j = pair & 31;
    int h2 = threadIdx.x * 2;           // 0,2,..,510

    int si = ids[((b * KK + i) << 1)];
    int ei = ids[((b * KK + i) << 1) + 1];
    int sj = ids[((b * KK + j) << 1)];
    int ej = ids[((b * KK + j) << 1) + 1];
    int me = min(ei, ej);
    int ms = max(si, sj);

    const float* head = cand + ((size_t)b * KK + i) * HH;
    const float* tail = cand + ((size_t)b * KK + j) * HH;
    bf16* outp = rel + (size_t)pair * K1;

    float2 hv = *(const float2*)(head + h2);
    float2 tv = *(const float2*)(tail + h2);
    bf16x2 o;
    o.x = __float2bfloat16(hv.x); o.y = __float2bfloat16(hv.y);
    *(bf16x2*)(outp + h2) = o;
    o.x = __float2bfloat16(tv.x); o.y = __float2bfloat16(tv.y);
    *(bf16x2*)(outp + HH + h2) = o;

    bf16* ctx = outp + 2 * HH;
    if (me < ms) {
        int L = ms - me;
        float m0 = -INFINITY, m1 = -INFINITY;
        if (L < 4) {
            const float* tb = tok + (size_t)b * SS * HH;
            for (int tt = me; tt < ms; ++tt) {
                float2 v = *(const float2*)(tb + (size_t)tt * HH + h2);
                m0 = fmaxf(m0, v.x);
                m1 = fmaxf(m1, v.y);
            }
        } else {
            int lvl = (L < 16) ? 0 : (L < 64) ? 1 : (L < 256) ? 2 : 3;
            int q = 4 << (2 * lvl);
            const bf16* base = tbl + (size_t)lvl * TBL_LVL_STRIDE + (size_t)b * SS * HH;
#pragma unroll
            for (int jj = 0; jj < 4; ++jj) {
                int p = min(me + jj * q, ms - q);
                bf16x2 v = *(const bf16x2*)(base + (size_t)p * HH + h2);
                m0 = fmaxf(m0, bf2f(v.x));
                m1 = fmaxf(m1, bf2f(v.y));
            }
        }
        o.x = __float2bfloat16(m0);
        o.y = __float2bfloat16(m1);
        *(bf16x2*)(ctx + h2) = o;
    } else {
        o.x = __float2bfloat16(hv.x);
        o.y = __float2bfloat16(hv.y);
        *(bf16x2*)(ctx + h2) = o;
    }
}

// ---------------------------------------------------------------------------
__device__ __forceinline__ void gload_lds16(const bf16* g, bf16* l)
{
    __builtin_amdgcn_global_load_lds(
        (const __attribute__((address_space(1))) unsigned int*)g,
        (__attribute__((address_space(3))) unsigned int*)l,
        16, 0, 0);
}

#define BAR() asm volatile("s_barrier" ::: "memory")
#define VMCNT0() asm volatile("s_waitcnt vmcnt(0)" ::: "memory")

// ---------------------------------------------------------------------------
// gemm_2ph (round-5 champion, measured 44.7 us on GEMM1): 128 x BN_ tile,
// BK=64, 4 waves (2Mx2N: wave = 64 x BN_/2), DOUBLE-buffered LDS, 2 blocks/CU
// co-residency hides the vmcnt(0) drain (m103/m114). 16B-chunk XOR swizzle
// (both sides, rule #21), chunked XCD swizzle. Optional split-K via nper.
//   GEMM1: BN_=96, grid 32x24=768 = exactly 3 blocks/CU (uniform makespan).
//   GEMM2: BN_=64, grid 32x8=256 = 1 block/CU, NT=36, NO split (writes d_out
//          f32 directly with fused bias -> kills P round-trip + reduce pass).
// ---------------------------------------------------------------------------
template <int BN_, bool RELU, bool OUT_BF16, bool ADD_BIAS>
__global__ __launch_bounds__(256, 2) void gemm_2ph(
    const bf16* __restrict__ A,    // [M_PAIRS][lda]
    const bf16* __restrict__ BT,   // [*][ldb]
    const float* __restrict__ bias,
    void* __restrict__ Cout,       // [M_PAIRS][ldc] per split
    int lda, int ldb, int NT, int nbn, int nper, int ldc)
{
    constexpr int NF = BN_ / 32;             // n-frags per wave (3 or 2)
    constexpr int AELEMS = 128 * 64;
    constexpr int TILE_E = (128 + BN_) * 64;
    __shared__ __align__(16) bf16 lds[2][TILE_E];

    // chunked XCD swizzle (gridDim.x % 8 == 0)
    const int nwg = gridDim.x;
    const int cpx = nwg >> 3;
    const int bid = blockIdx.x;
    const int wg = (bid & 7) * cpx + (bid >> 3);

    const int s   = wg / nper;
    const int rem = wg - s * nper;
    const int bm  = rem / nbn;
    const int bn  = rem - bm * nbn;
    const int row0 = bm * 128;
    const int col0 = bn * BN_;

    const bf16* As = A  + (size_t)s * NT * 64;   // K-split offset
    const bf16* Bs = BT + (size_t)s * NT * 64;

    const int tid = threadIdx.x;
    const int w = tid >> 6, l = tid & 63;
    const int wm = w >> 1;          // 0..1 -> rows wm*64..+63
    const int wn = w & 1;           // 0..1 -> cols wn*(BN_/2)..

    // staging lane constants (pre-swizzled source chunk; linear LDS dest)
    const int lr  = l >> 3;         // 0..7
    const int lch = (l & 7) ^ lr;
    // ds_read swizzled offsets (row&7 == l&7 for all reads below)
    const int l15 = l & 15;
    const int sw0 = (((l >> 4)    ) ^ (l & 7)) * 16;
    const int sw1 = (((l >> 4) + 4) ^ (l & 7)) * 16;

    auto stage = [&](int ts, int sb) {
        // A: each wave stages rows w*32 + j*8 + lr (j<4) -> 128 rows
        const bf16* ga = As + (size_t)(row0 + w * 32 + lr) * lda + ts * 64 + lch * 8;
        bf16* da = &lds[sb][(w * 32) * 64];
#pragma unroll
        for (int j = 0; j < 4; ++j)
            gload_lds16(ga + (size_t)(j * 8) * lda, da + j * 512);
        // B: each wave stages rows w*(BN_/4) + j*8 + lr (j<NF) -> BN_ rows
        const bf16* gb = Bs + (size_t)(col0 + w * (BN_ / 4) + lr) * ldb + ts * 64 + lch * 8;
        bf16* db = &lds[sb][AELEMS + (w * (BN_ / 4)) * 64];
#pragma unroll
        for (int j = 0; j < NF; ++j)
            gload_lds16(gb + (size_t)(j * 8) * ldb, db + j * 512);
    };

    f32x4 acc[4][NF] = {};

    stage(0, 0);
    VMCNT0();
    BAR();

    for (int t = 0; t < NT; ++t) {
        const int sb = t & 1;
        if (t + 1 < NT) stage(t + 1, sb ^ 1);   // issue next-tile loads FIRST
        const char* Ab = (const char*)&lds[sb][0];
        const char* Bb = (const char*)&lds[sb][AELEMS];
        bf16x8 af[4][2], bfr[NF][2];
#pragma unroll
        for (int m = 0; m < 4; ++m) {
            const char* p = Ab + (wm * 64 + m * 16 + l15) * 128;
            af[m][0] = *(const bf16x8*)(p + sw0);
            af[m][1] = *(const bf16x8*)(p + sw1);
        }
#pragma unroll
        for (int n = 0; n < NF; ++n) {
            const char* p = Bb + (wn * (BN_ / 2) + n * 16 + l15) * 128;
            bfr[n][0] = *(const bf16x8*)(p + sw0);
            bfr[n][1] = *(const bf16x8*)(p + sw1);
        }
#pragma unroll
        for (int m = 0; m < 4; ++m)
#pragma unroll
            for (int n = 0; n < NF; ++n)
#pragma unroll
                for (int kk = 0; kk < 2; ++kk)
                    acc[m][n] = __builtin_amdgcn_mfma_f32_16x16x32_bf16(
                        af[m][kk], bfr[n][kk], acc[m][n], 0, 0, 0);
        // boundary: next tile's loads must land before anyone reads buf^1
        VMCNT0();
        BAR();
    }

    // epilogue. C/D: col=lane&15, row=(lane>>4)*4+q
    const int crow = (l >> 4) * 4;
    char* outBase = (char*)Cout + (size_t)s * M_PAIRS * ldc * (OUT_BF16 ? 2 : 4);
#pragma unroll
    for (int m = 0; m < 4; ++m) {
        int row = row0 + wm * 64 + m * 16 + crow;
#pragma unroll
        for (int n = 0; n < NF; ++n) {
            int col = col0 + wn * (BN_ / 2) + n * 16 + l15;
            float bv = ADD_BIAS ? bias[col] : 0.f;
#pragma unroll
            for (int q = 0; q < 4; ++q) {
                float v = acc[m][n][q] + bv;
                if (RELU) v = fmaxf(v, 0.f);
                size_t idx = (size_t)(row + q) * ldc + col;
                if (OUT_BF16)
                    ((bf16*)outBase)[idx] = __float2bfloat16(v);
                else
                    ((float*)outBase)[idx] = v;
            }
        }
    }
}

// ---------------------------------------------------------------------------
extern "C" void kernel_launch(void* const* d_in, const int* in_sizes, int n_in,
                              void* d_out, int out_size, void* d_ws, size_t ws_size,
                              hipStream_t stream)
{
    const float* cand = (const float*)d_in[0];
    const float* tok  = (const float*)d_in[1];
    const float* W1   = (const float*)d_in[2];
    const float* b1   = (const float*)d_in[3];
    const float* W2   = (const float*)d_in[4];
    const float* b2   = (const float*)d_in[5];
    const int*   ids  = (const int*)d_in[6];
    float* out = (float*)d_out;

    char* ws = (char*)d_ws;
    const size_t relB_sz = (size_t)M_PAIRS * K1 * 2;        // 12,582,912
    const size_t w1t_sz  = (size_t)FFN * K1 * 2;            //  7,077,888
    const size_t w2t_sz  = (size_t)HH * FFN * 2;            //  2,359,296
    bf16* relB = (bf16*)ws;
    bf16* W1T  = (bf16*)(ws + relB_sz);
    bf16* W2T  = (bf16*)(ws + relB_sz + w1t_sz);
    char* regionX = ws + relB_sz + w1t_sz + w2t_sz;
    bf16* tbl = (bf16*)regionX;   // 16 MB, dead after build_rel
    bf16* hid = (bf16*)regionX;   // 18.9 MB, written by GEMM1 afterwards

    // 1) weight transpose+cast (one kernel for both W1 and W2)
    transpose_both<<<W1_TILES + W2_TILES, 256, 0, stream>>>(W1, W1T, W2, W2T);

    // 2) sparse range-max tables: l0+l1 fused, then l2+l3 fused
    build_table_A<<<BB * SS, 256, 0, stream>>>(
        tok, tbl + 0 * TBL_LVL_STRIDE, tbl + 1 * TBL_LVL_STRIDE);
    build_table_B<<<BB * SS, 256, 0, stream>>>(
        tbl + 1 * TBL_LVL_STRIDE, tbl + 2 * TBL_LVL_STRIDE,
        tbl + 3 * TBL_LVL_STRIDE);

    // 3) build rel = [heads|tails|context] bf16
    build_rel<<<M_PAIRS, 256, 0, stream>>>(cand, tok, ids, tbl, relB);

    // 4) hid = relu(rel @ W1 + b1) -> bf16. Round-5 champion config:
    //    128x96 tiles, grid 32x24 = 768 = 3 blocks/CU at 2-block co-residency.
    gemm_2ph<96, true, true, true><<<768, 256, 0, stream>>>(
        relB, W1T, b1, hid, K1, K1, /*NT=*/24, /*nbn=*/24, /*nper=*/768, FFN);

    // 5) out = hid @ W2 + b2 -> f32 directly (no split-K, no P round-trip,
    //    no reduce kernel). 128x64 tiles, grid 32x8 = 256 = 1 block/CU.
    gemm_2ph<64, false, false, true><<<256, 256, 0, stream>>>(
        hid, W2T, b2, out, FFN, FFN, /*NT=*/36, /*nbn=*/8, /*nper=*/256, HH);
}

// Round 9
// 84.020 us; speedup vs baseline: 1.8306x; 1.1665x over previous
//
#include <hip/hip_runtime.h>
#include <hip/hip_bf16.h>
#include <cstdint>

// Problem constants (reference: B=4, K=32, S=1024, H=512, FFN=2304)
#define BB 4
#define KK 32
#define SS 1024
#define HH 512
#define FFN 2304
#define M_PAIRS (BB * KK * KK)   // 4096
#define K1 (3 * HH)              // 1536

using bf16 = __hip_bfloat16;
using f32x4 = __attribute__((ext_vector_type(4))) float;
using bf16x8 = __attribute__((ext_vector_type(8))) short;

struct bf16x2 { bf16 x, y; };

__device__ __forceinline__ float bf2f(bf16 v) { return __bfloat162float(v); }

// ---------------------------------------------------------------------------
// Fused: W1[1536][2304] -> W1T[2304][1536] bf16, W2[2304][512] -> W2T[512][2304]
// bf16, and cand[128][512] f32 -> candB bf16 (no transpose).
// ---------------------------------------------------------------------------
#define W1_TILES (72 * 48)     // (2304/32) x (1536/32)
#define W2_TILES (16 * 72)     // (512/32)  x (2304/32)
#define CAND_BLKS 128          // 128*512 elems / (256 thr * 2)

__global__ __launch_bounds__(256) void transpose_both(
    const float* __restrict__ W1, bf16* __restrict__ W1T,
    const float* __restrict__ W2, bf16* __restrict__ W2T,
    const float* __restrict__ cand, bf16* __restrict__ candB)
{
    int bid = blockIdx.x;
    if (bid >= W1_TILES + W2_TILES) {       // cand f32 -> bf16 cast
        int idx = ((bid - W1_TILES - W2_TILES) * 256 + threadIdx.x) * 2;
        float2 v = *(const float2*)(cand + idx);
        bf16x2 o;
        o.x = __float2bfloat16(v.x);
        o.y = __float2bfloat16(v.y);
        *(bf16x2*)(candB + idx) = o;
        return;
    }
    __shared__ float tile[32][33];
    const float* in; bf16* out; int R, C, bx, by;
    if (bid < W1_TILES) {
        in = W1; out = W1T; R = K1; C = FFN;
        bx = bid % 72; by = bid / 72;
    } else {
        bid -= W1_TILES;
        in = W2; out = W2T; R = FFN; C = HH;
        bx = bid % 16; by = bid / 16;
    }
    int bc = bx * 32, br = by * 32;
    int tx = threadIdx.x & 31;
    int ty = threadIdx.x >> 5;
#pragma unroll
    for (int i = 0; i < 32; i += 8)
        tile[ty + i][tx] = in[(size_t)(br + ty + i) * C + bc + tx];
    __syncthreads();
#pragma unroll
    for (int i = 0; i < 32; i += 8)
        out[(size_t)(bc + ty + i) * R + br + tx] = __float2bfloat16(tile[tx][ty + i]);
}

// ---------------------------------------------------------------------------
// Sparse range-max tables, window sizes q = 4,16,64,256, bf16 (fused 2+2).
// In-range entries (t <= S-q, the only ones queried) are exact window maxima.
// ---------------------------------------------------------------------------
#define TBL_LVL_STRIDE ((size_t)BB * SS * HH)

__global__ __launch_bounds__(256) void build_table_A(
    const float* __restrict__ tok, bf16* __restrict__ tbl0,
    bf16* __restrict__ tbl1)
{
    int bt = ((blockIdx.x & 7) << 9) + (blockIdx.x >> 3);
    int b = bt >> 10, t = bt & 1023;
    int h0 = threadIdx.x * 2;
    const float* base = tok + (size_t)b * SS * HH;
    float m0 = -INFINITY, m1 = -INFINITY;
    float l00 = 0.f, l01 = 0.f;
#pragma unroll
    for (int j = 0; j < 16; ++j) {
        int tt = min(t + j, SS - 1);
        float2 v = *(const float2*)(base + (size_t)tt * HH + h0);
        m0 = fmaxf(m0, v.x);
        m1 = fmaxf(m1, v.y);
        if (j == 3) { l00 = m0; l01 = m1; }
    }
    bf16x2 o;
    o.x = __float2bfloat16(l00);
    o.y = __float2bfloat16(l01);
    *(bf16x2*)(tbl0 + (size_t)bt * HH + h0) = o;
    o.x = __float2bfloat16(m0);
    o.y = __float2bfloat16(m1);
    *(bf16x2*)(tbl1 + (size_t)bt * HH + h0) = o;
}

__global__ __launch_bounds__(256) void build_table_B(
    const bf16* __restrict__ tbl1, bf16* __restrict__ tbl2,
    bf16* __restrict__ tbl3)
{
    int bt = ((blockIdx.x & 7) << 9) + (blockIdx.x >> 3);
    int b = bt >> 10, t = bt & 1023;
    int h0 = threadIdx.x * 2;
    const bf16* base = tbl1 + (size_t)b * SS * HH;
    float m0 = -INFINITY, m1 = -INFINITY;
    float l20 = 0.f, l21 = 0.f;
#pragma unroll
    for (int j = 0; j < 16; ++j) {
        int tt = min(t + j * 16, SS - 16);
        bf16x2 v = *(const bf16x2*)(base + (size_t)tt * HH + h0);
        m0 = fmaxf(m0, bf2f(v.x));
        m1 = fmaxf(m1, bf2f(v.y));
        if (j == 3) { l20 = m0; l21 = m1; }
    }
    bf16x2 o;
    o.x = __float2bfloat16(l20);
    o.y = __float2bfloat16(l21);
    *(bf16x2*)(tbl2 + (size_t)bt * HH + h0) = o;
    o.x = __float2bfloat16(m0);
    o.y = __float2bfloat16(m1);
    *(bf16x2*)(tbl3 + (size_t)bt * HH + h0) = o;
}

// ---------------------------------------------------------------------------
// build_ctx: one block per pair (b,i,j); writes ONLY the ctx 512-row
// (valid: range-max via table; invalid: head = cand[b,i]).
// ---------------------------------------------------------------------------
__global__ __launch_bounds__(256) void build_ctx(
    const float* __restrict__ cand,
    const float* __restrict__ tok,
    const int* __restrict__ ids,
    const bf16* __restrict__ tbl,
    bf16* __restrict__ ctxB)          // [M_PAIRS][512]
{
    int pair = blockIdx.x;
    int b = pair >> 10;
    int i = (pair >> 5) & 31;
    int j = pair & 31;
    int h2 = threadIdx.x * 2;

    int si = ids[((b * KK + i) << 1)];
    int ei = ids[((b * KK + i) << 1) + 1];
    int sj = ids[((b * KK + j) << 1)];
    int ej = ids[((b * KK + j) << 1) + 1];
    int me = min(ei, ej);
    int ms = max(si, sj);

    bf16* ctx = ctxB + (size_t)pair * HH;
    bf16x2 o;
    if (me < ms) {
        int L = ms - me;
        float m0 = -INFINITY, m1 = -INFINITY;
        if (L < 4) {
            const float* tb = tok + (size_t)b * SS * HH;
            for (int tt = me; tt < ms; ++tt) {
                float2 v = *(const float2*)(tb + (size_t)tt * HH + h2);
                m0 = fmaxf(m0, v.x);
                m1 = fmaxf(m1, v.y);
            }
        } else {
            int lvl = (L < 16) ? 0 : (L < 64) ? 1 : (L < 256) ? 2 : 3;
            int q = 4 << (2 * lvl);
            const bf16* base = tbl + (size_t)lvl * TBL_LVL_STRIDE + (size_t)b * SS * HH;
#pragma unroll
            for (int jj = 0; jj < 4; ++jj) {
                int p = min(me + jj * q, ms - q);
                bf16x2 v = *(const bf16x2*)(base + (size_t)p * HH + h2);
                m0 = fmaxf(m0, bf2f(v.x));
                m1 = fmaxf(m1, bf2f(v.y));
            }
        }
        o.x = __float2bfloat16(m0);
        o.y = __float2bfloat16(m1);
    } else {
        float2 hv = *(const float2*)(cand + ((size_t)b * KK + i) * HH + h2);
        o.x = __float2bfloat16(hv.x);
        o.y = __float2bfloat16(hv.y);
    }
    *(bf16x2*)(ctx + h2) = o;
}

// ---------------------------------------------------------------------------
__device__ __forceinline__ void gload_lds16(const bf16* g, bf16* l)
{
    __builtin_amdgcn_global_load_lds(
        (const __attribute__((address_space(1))) unsigned int*)g,
        (__attribute__((address_space(3))) unsigned int*)l,
        16, 0, 0);
}

#define BAR() asm volatile("s_barrier" ::: "memory")
#define VMCNT0() asm volatile("s_waitcnt vmcnt(0)" ::: "memory")

// ---------------------------------------------------------------------------
// gemm_2ph (round-5/8 champion structure): 128 x BN_ tile, BK=64, 4 waves
// (2Mx2N), double-buffered LDS, vmcnt(0)+barrier per tile (2 blocks/CU
// co-residency hides the drain), 16B-chunk XOR swizzle both sides,
// chunked XCD swizzle.
// MODE 0: standard (s = K-split index via nper; GEMM2 uses s=0).
// MODE 1: B-only split (s picks k-offset s*NT*64 in BT and out-row block
//         s*mrows; A unsplit) -> computes Hh (s=0) and Ht (s=1) in one grid.
// MODE 2: +HT epilogue: v = acc + b1[col] + Hh[ih][col] + Ht[jt][col], relu.
// ---------------------------------------------------------------------------
template <int BN_, bool RELU, bool OUT_BF16, bool ADD_BIAS, int MODE>
__global__ __launch_bounds__(256, 2) void gemm_2ph(
    const bf16* __restrict__ A,    // [*][lda]
    const bf16* __restrict__ BT,   // [*][ldb]
    const float* __restrict__ bias,
    const float* __restrict__ hh,  // MODE2: HhHt base [2][128][FFN] f32
    void* __restrict__ Cout,
    int lda, int ldb, int NT, int nbn, int nper, int ldc, int mrows)
{
    constexpr int NF = BN_ / 32;             // n-frags per wave (3 or 2)
    constexpr int AELEMS = 128 * 64;
    constexpr int TILE_E = (128 + BN_) * 64;
    __shared__ __align__(16) bf16 lds[2][TILE_E];

    // chunked XCD swizzle (gridDim.x % 8 == 0)
    const int nwg = gridDim.x;
    const int cpx = nwg >> 3;
    const int bid = blockIdx.x;
    const int wg = (bid & 7) * cpx + (bid >> 3);

    const int s   = wg / nper;
    const int rem = wg - s * nper;
    const int bm  = rem / nbn;
    const int bn  = rem - bm * nbn;
    const int row0 = bm * 128;
    const int col0 = bn * BN_;

    const bf16* As = A  + (MODE == 1 ? (size_t)0 : (size_t)s * NT * 64);
    const bf16* Bs = BT + (size_t)s * NT * 64;

    const int tid = threadIdx.x;
    const int w = tid >> 6, l = tid & 63;
    const int wm = w >> 1;          // 0..1 -> rows wm*64..+63
    const int wn = w & 1;           // 0..1 -> cols wn*(BN_/2)..

    // staging lane constants (pre-swizzled source chunk; linear LDS dest)
    const int lr  = l >> 3;         // 0..7
    const int lch = (l & 7) ^ lr;
    // ds_read swizzled offsets (row&7 == l&7 for all reads below)
    const int l15 = l & 15;
    const int sw0 = (((l >> 4)    ) ^ (l & 7)) * 16;
    const int sw1 = (((l >> 4) + 4) ^ (l & 7)) * 16;

    auto stage = [&](int ts, int sb) {
        const bf16* ga = As + (size_t)(row0 + w * 32 + lr) * lda + ts * 64 + lch * 8;
        bf16* da = &lds[sb][(w * 32) * 64];
#pragma unroll
        for (int j = 0; j < 4; ++j)
            gload_lds16(ga + (size_t)(j * 8) * lda, da + j * 512);
        const bf16* gb = Bs + (size_t)(col0 + w * (BN_ / 4) + lr) * ldb + ts * 64 + lch * 8;
        bf16* db = &lds[sb][AELEMS + (w * (BN_ / 4)) * 64];
#pragma unroll
        for (int j = 0; j < NF; ++j)
            gload_lds16(gb + (size_t)(j * 8) * ldb, db + j * 512);
    };

    f32x4 acc[4][NF] = {};

    stage(0, 0);
    VMCNT0();
    BAR();

    for (int t = 0; t < NT; ++t) {
        const int sb = t & 1;
        if (t + 1 < NT) stage(t + 1, sb ^ 1);   // issue next-tile loads FIRST
        const char* Ab = (const char*)&lds[sb][0];
        const char* Bb = (const char*)&lds[sb][AELEMS];
        bf16x8 af[4][2], bfr[NF][2];
#pragma unroll
        for (int m = 0; m < 4; ++m) {
            const char* p = Ab + (wm * 64 + m * 16 + l15) * 128;
            af[m][0] = *(const bf16x8*)(p + sw0);
            af[m][1] = *(const bf16x8*)(p + sw1);
        }
#pragma unroll
        for (int n = 0; n < NF; ++n) {
            const char* p = Bb + (wn * (BN_ / 2) + n * 16 + l15) * 128;
            bfr[n][0] = *(const bf16x8*)(p + sw0);
            bfr[n][1] = *(const bf16x8*)(p + sw1);
        }
#pragma unroll
        for (int m = 0; m < 4; ++m)
#pragma unroll
            for (int n = 0; n < NF; ++n)
#pragma unroll
                for (int kk = 0; kk < 2; ++kk)
                    acc[m][n] = __builtin_amdgcn_mfma_f32_16x16x32_bf16(
                        af[m][kk], bfr[n][kk], acc[m][n], 0, 0, 0);
        VMCNT0();
        BAR();
    }

    // epilogue. C/D: col=lane&15, row=(lane>>4)*4+q
    const int crow = (l >> 4) * 4;
    char* outBase = (char*)Cout + (size_t)s * mrows * ldc * (OUT_BF16 ? 2 : 4);
    const float* htp = (MODE == 2) ? hh + (size_t)128 * FFN : nullptr;
    const int bq32 = (row0 >> 10) * 32;      // b*32 (MODE 2)
#pragma unroll
    for (int m = 0; m < 4; ++m) {
        int row = row0 + wm * 64 + m * 16 + crow;
        int ih = ((row0 + wm * 64) >> 5) + (m >> 1);        // MODE 2: b*32+i
#pragma unroll
        for (int n = 0; n < NF; ++n) {
            int col = col0 + wn * (BN_ / 2) + n * 16 + l15;
            float bv = ADD_BIAS ? bias[col] : 0.f;
#pragma unroll
            for (int q = 0; q < 4; ++q) {
                float v = acc[m][n][q] + bv;
                if (MODE == 2) {
                    int jt = bq32 + (m & 1) * 16 + crow + q; // b*32+j
                    v += hh[(size_t)ih * FFN + col] + htp[(size_t)jt * FFN + col];
                }
                if (RELU) v = fmaxf(v, 0.f);
                size_t idx = (size_t)(row + q) * ldc + col;
                if (OUT_BF16)
                    ((bf16*)outBase)[idx] = __float2bfloat16(v);
                else
                    ((float*)outBase)[idx] = v;
            }
        }
    }
}

// ---------------------------------------------------------------------------
extern "C" void kernel_launch(void* const* d_in, const int* in_sizes, int n_in,
                              void* d_out, int out_size, void* d_ws, size_t ws_size,
                              hipStream_t stream)
{
    const float* cand = (const float*)d_in[0];
    const float* tok  = (const float*)d_in[1];
    const float* W1   = (const float*)d_in[2];
    const float* b1   = (const float*)d_in[3];
    const float* W2   = (const float*)d_in[4];
    const float* b2   = (const float*)d_in[5];
    const int*   ids  = (const int*)d_in[6];
    float* out = (float*)d_out;

    char* ws = (char*)d_ws;
    const size_t ctx_sz  = (size_t)M_PAIRS * HH * 2;        //  4,194,304
    const size_t cnd_sz  = (size_t)BB * KK * HH * 2;        //    131,072
    const size_t w1t_sz  = (size_t)FFN * K1 * 2;            //  7,077,888
    const size_t w2t_sz  = (size_t)HH * FFN * 2;            //  2,359,296
    const size_t hht_sz  = (size_t)2 * 128 * FFN * 4;       //  2,359,296
    bf16*  ctxB  = (bf16*)ws;
    bf16*  candB = (bf16*)(ws + ctx_sz);
    bf16*  W1T   = (bf16*)(ws + ctx_sz + cnd_sz);
    bf16*  W2T   = (bf16*)(ws + ctx_sz + cnd_sz + w1t_sz);
    float* HhHt  = (float*)(ws + ctx_sz + cnd_sz + w1t_sz + w2t_sz);
    char* regionX = ws + ctx_sz + cnd_sz + w1t_sz + w2t_sz + hht_sz;
    bf16* tbl = (bf16*)regionX;   // 16 MB, dead after build_ctx
    bf16* hid = (bf16*)regionX;   // 18.9 MB, written by gemm1c afterwards

    // 1) weight transposes + cand bf16 cast (one kernel)
    transpose_both<<<W1_TILES + W2_TILES + CAND_BLKS, 256, 0, stream>>>(
        W1, W1T, W2, W2T, cand, candB);

    // 2) sparse range-max tables: l0+l1 fused, then l2+l3 fused
    build_table_A<<<BB * SS, 256, 0, stream>>>(
        tok, tbl + 0 * TBL_LVL_STRIDE, tbl + 1 * TBL_LVL_STRIDE);
    build_table_B<<<BB * SS, 256, 0, stream>>>(
        tbl + 1 * TBL_LVL_STRIDE, tbl + 2 * TBL_LVL_STRIDE,
        tbl + 3 * TBL_LVL_STRIDE);

    // 3) GEMM1a: Hh = candB @ W1T[:,0:512]^T, Ht = candB @ W1T[:,512:1024]^T.
    //    M=128, N=2304, K=512 (NT=8). One grid of 2x24 = 48 blocks (s picks half).
    gemm_2ph<96, false, false, false, 1><<<48, 256, 0, stream>>>(
        candB, W1T, nullptr, nullptr, HhHt,
        HH, K1, /*NT=*/8, /*nbn=*/24, /*nper=*/24, FFN, /*mrows=*/128);

    // 4) build ctx rows only (valid: table range-max; invalid: head)
    build_ctx<<<M_PAIRS, 256, 0, stream>>>(cand, tok, ids, tbl, ctxB);

    // 5) GEMM1c: hid = relu(ctxB @ W1T[:,1024:1536]^T + Hh[i] + Ht[j] + b1).
    //    K=512 (NT=8), champion 128x96 grid 32x24 = 768 = 3 blocks/CU.
    gemm_2ph<96, true, true, true, 2><<<768, 256, 0, stream>>>(
        ctxB, W1T + 1024, b1, HhHt, hid,
        HH, K1, /*NT=*/8, /*nbn=*/24, /*nper=*/768, FFN, /*mrows=*/0);

    // 6) out = hid @ W2 + b2 -> f32 directly. 128x64 tiles, grid 256.
    gemm_2ph<64, false, false, true, 0><<<256, 256, 0, stream>>>(
        hid, W2T, b2, nullptr, out,
        FFN, FFN, /*NT=*/36, /*nbn=*/8, /*nper=*/256, HH, /*mrows=*/0);
}

// Round 10
// 78.503 us; speedup vs baseline: 1.9592x; 1.0703x over previous
//
#include <hip/hip_runtime.h>
#include <hip/hip_bf16.h>
#include <cstdint>

// Problem constants (reference: B=4, K=32, S=1024, H=512, FFN=2304)
#define BB 4
#define KK 32
#define SS 1024
#define HH 512
#define FFN 2304
#define M_PAIRS (BB * KK * KK)   // 4096
#define K1 (3 * HH)              // 1536

using bf16 = __hip_bfloat16;
using f32x4 = __attribute__((ext_vector_type(4))) float;
using bf16x8 = __attribute__((ext_vector_type(8))) short;

struct bf16x2 { bf16 x, y; };

__device__ __forceinline__ float bf2f(bf16 v) { return __bfloat162float(v); }
__device__ __forceinline__ float b2fr(short s) {
    unsigned u = ((unsigned)(unsigned short)s) << 16;
    float f; __builtin_memcpy(&f, &u, 4); return f;
}
__device__ __forceinline__ short f2br(float f) {
    bf16 h = __float2bfloat16(f);
    short s; __builtin_memcpy(&s, &h, 2); return s;
}

// ---------------------------------------------------------------------------
// Fused: W1 -> W1T bf16, W2 -> W2T bf16, cand f32 -> candB bf16.
// ---------------------------------------------------------------------------
#define W1_TILES (72 * 48)     // (2304/32) x (1536/32)
#define W2_TILES (16 * 72)     // (512/32)  x (2304/32)
#define CAND_BLKS 128          // 128*512 elems / (256 thr * 2)

__global__ __launch_bounds__(256) void transpose_both(
    const float* __restrict__ W1, bf16* __restrict__ W1T,
    const float* __restrict__ W2, bf16* __restrict__ W2T,
    const float* __restrict__ cand, bf16* __restrict__ candB)
{
    int bid = blockIdx.x;
    if (bid >= W1_TILES + W2_TILES) {       // cand f32 -> bf16 cast
        int idx = ((bid - W1_TILES - W2_TILES) * 256 + threadIdx.x) * 2;
        float2 v = *(const float2*)(cand + idx);
        bf16x2 o;
        o.x = __float2bfloat16(v.x);
        o.y = __float2bfloat16(v.y);
        *(bf16x2*)(candB + idx) = o;
        return;
    }
    __shared__ float tile[32][33];
    const float* in; bf16* out; int R, C, bx, by;
    if (bid < W1_TILES) {
        in = W1; out = W1T; R = K1; C = FFN;
        bx = bid % 72; by = bid / 72;
    } else {
        bid -= W1_TILES;
        in = W2; out = W2T; R = FFN; C = HH;
        bx = bid % 16; by = bid / 16;
    }
    int bc = bx * 32, br = by * 32;
    int tx = threadIdx.x & 31;
    int ty = threadIdx.x >> 5;
#pragma unroll
    for (int i = 0; i < 32; i += 8)
        tile[ty + i][tx] = in[(size_t)(br + ty + i) * C + bc + tx];
    __syncthreads();
#pragma unroll
    for (int i = 0; i < 32; i += 8)
        out[(size_t)(bc + ty + i) * R + br + tx] = __float2bfloat16(tile[tx][ty + i]);
}

// ---------------------------------------------------------------------------
// Sparse range-max tables, window sizes q = 4,16,64,256, bf16 (fused 2+2).
// ---------------------------------------------------------------------------
#define TBL_LVL_STRIDE ((size_t)BB * SS * HH)

__global__ __launch_bounds__(256) void build_table_A(
    const float* __restrict__ tok, bf16* __restrict__ tbl0,
    bf16* __restrict__ tbl1)
{
    int bt = ((blockIdx.x & 7) << 9) + (blockIdx.x >> 3);
    int b = bt >> 10, t = bt & 1023;
    int h0 = threadIdx.x * 2;
    const float* base = tok + (size_t)b * SS * HH;
    float m0 = -INFINITY, m1 = -INFINITY;
    float l00 = 0.f, l01 = 0.f;
#pragma unroll
    for (int j = 0; j < 16; ++j) {
        int tt = min(t + j, SS - 1);
        float2 v = *(const float2*)(base + (size_t)tt * HH + h0);
        m0 = fmaxf(m0, v.x);
        m1 = fmaxf(m1, v.y);
        if (j == 3) { l00 = m0; l01 = m1; }
    }
    bf16x2 o;
    o.x = __float2bfloat16(l00);
    o.y = __float2bfloat16(l01);
    *(bf16x2*)(tbl0 + (size_t)bt * HH + h0) = o;
    o.x = __float2bfloat16(m0);
    o.y = __float2bfloat16(m1);
    *(bf16x2*)(tbl1 + (size_t)bt * HH + h0) = o;
}

__global__ __launch_bounds__(256) void build_table_B(
    const bf16* __restrict__ tbl1, bf16* __restrict__ tbl2,
    bf16* __restrict__ tbl3)
{
    int bt = ((blockIdx.x & 7) << 9) + (blockIdx.x >> 3);
    int b = bt >> 10, t = bt & 1023;
    int h0 = threadIdx.x * 2;
    const bf16* base = tbl1 + (size_t)b * SS * HH;
    float m0 = -INFINITY, m1 = -INFINITY;
    float l20 = 0.f, l21 = 0.f;
#pragma unroll
    for (int j = 0; j < 16; ++j) {
        int tt = min(t + j * 16, SS - 16);
        bf16x2 v = *(const bf16x2*)(base + (size_t)tt * HH + h0);
        m0 = fmaxf(m0, bf2f(v.x));
        m1 = fmaxf(m1, bf2f(v.y));
        if (j == 3) { l20 = m0; l21 = m1; }
    }
    bf16x2 o;
    o.x = __float2bfloat16(l20);
    o.y = __float2bfloat16(l21);
    *(bf16x2*)(tbl2 + (size_t)bt * HH + h0) = o;
    o.x = __float2bfloat16(m0);
    o.y = __float2bfloat16(m1);
    *(bf16x2*)(tbl3 + (size_t)bt * HH + h0) = o;
}

// ---------------------------------------------------------------------------
// build_ctx: ONE WAVE per pair (4 pairs/block). Lane l owns 8 elems (16B).
// valid: range-max via <=4 16B table loads; invalid: head = cand[b,i].
// ---------------------------------------------------------------------------
__global__ __launch_bounds__(256) void build_ctx(
    const float* __restrict__ cand,
    const float* __restrict__ tok,
    const int* __restrict__ ids,
    const bf16* __restrict__ tbl,
    bf16* __restrict__ ctxB)          // [M_PAIRS][512]
{
    int w = threadIdx.x >> 6, l = threadIdx.x & 63;
    int pair = blockIdx.x * 4 + w;
    int b = pair >> 10;
    int i = (pair >> 5) & 31;
    int j = pair & 31;
    int h0 = l * 8;

    int si = ids[((b * KK + i) << 1)];
    int ei = ids[((b * KK + i) << 1) + 1];
    int sj = ids[((b * KK + j) << 1)];
    int ej = ids[((b * KK + j) << 1) + 1];
    int me = min(ei, ej);
    int ms = max(si, sj);

    float m[8];
    bf16x8 o;
    if (me < ms) {
        int L = ms - me;
#pragma unroll
        for (int e = 0; e < 8; ++e) m[e] = -INFINITY;
        if (L < 4) {
            const float* tb = tok + (size_t)b * SS * HH + h0;
            for (int tt = me; tt < ms; ++tt) {
                float4 v0 = *(const float4*)(tb + (size_t)tt * HH);
                float4 v1 = *(const float4*)(tb + (size_t)tt * HH + 4);
                m[0] = fmaxf(m[0], v0.x); m[1] = fmaxf(m[1], v0.y);
                m[2] = fmaxf(m[2], v0.z); m[3] = fmaxf(m[3], v0.w);
                m[4] = fmaxf(m[4], v1.x); m[5] = fmaxf(m[5], v1.y);
                m[6] = fmaxf(m[6], v1.z); m[7] = fmaxf(m[7], v1.w);
            }
        } else {
            int lvl = (L < 16) ? 0 : (L < 64) ? 1 : (L < 256) ? 2 : 3;
            int q = 4 << (2 * lvl);
            const bf16* base = tbl + (size_t)lvl * TBL_LVL_STRIDE
                               + (size_t)b * SS * HH + h0;
#pragma unroll
            for (int jj = 0; jj < 4; ++jj) {
                int p = min(me + jj * q, ms - q);
                bf16x8 v = *(const bf16x8*)(base + (size_t)p * HH);
#pragma unroll
                for (int e = 0; e < 8; ++e)
                    m[e] = fmaxf(m[e], b2fr(v[e]));
            }
        }
#pragma unroll
        for (int e = 0; e < 8; ++e) o[e] = f2br(m[e]);
    } else {
        const float* hp = cand + ((size_t)b * KK + i) * HH + h0;
        float4 v0 = *(const float4*)hp;
        float4 v1 = *(const float4*)(hp + 4);
        o[0] = f2br(v0.x); o[1] = f2br(v0.y); o[2] = f2br(v0.z); o[3] = f2br(v0.w);
        o[4] = f2br(v1.x); o[5] = f2br(v1.y); o[6] = f2br(v1.z); o[7] = f2br(v1.w);
    }
    *(bf16x8*)(ctxB + (size_t)pair * HH + h0) = o;
}

// ---------------------------------------------------------------------------
__device__ __forceinline__ void gload_lds16(const bf16* g, bf16* l)
{
    __builtin_amdgcn_global_load_lds(
        (const __attribute__((address_space(1))) unsigned int*)g,
        (__attribute__((address_space(3))) unsigned int*)l,
        16, 0, 0);
}

#define BAR() asm volatile("s_barrier" ::: "memory")
#define VMCNT0() asm volatile("s_waitcnt vmcnt(0)" ::: "memory")

// ---------------------------------------------------------------------------
// gemm_2ph (champion structure, generalized BM_): BM_ x BN_ tile, BK=64,
// 4 waves (2Mx2N), double-buffered LDS, vmcnt(0)+barrier per tile (>=2
// blocks/CU co-residency hides the drain), 16B-chunk XOR swizzle both sides,
// chunked XCD swizzle.
// MODE 0: standard.  MODE 1: B-only split (s -> k-offset + out-row block).
// MODE 2: +HT epilogue: v = acc + b1[col] + Hh[b*32+i][col] + Ht[b*32+j][col].
// ---------------------------------------------------------------------------
template <int BM_, int BN_, bool RELU, bool OUT_BF16, bool ADD_BIAS, int MODE>
__global__ __launch_bounds__(256, 2) void gemm_2ph(
    const bf16* __restrict__ A,    // [*][lda]
    const bf16* __restrict__ BT,   // [*][ldb]
    const float* __restrict__ bias,
    const float* __restrict__ hh,  // MODE2: HhHt base [2][128][FFN] f32
    void* __restrict__ Cout,
    int lda, int ldb, int NT, int nbn, int nper, int ldc, int mrows)
{
    constexpr int MFR = BM_ / 32;            // m-frags per wave
    constexpr int NF  = BN_ / 32;            // n-frags per wave
    constexpr int AELEMS = BM_ * 64;
    constexpr int TILE_E = (BM_ + BN_) * 64;
    __shared__ __align__(16) bf16 lds[2][TILE_E];

    // chunked XCD swizzle (gridDim.x % 8 == 0)
    const int nwg = gridDim.x;
    const int cpx = nwg >> 3;
    const int bid = blockIdx.x;
    const int wg = (bid & 7) * cpx + (bid >> 3);

    const int s   = wg / nper;
    const int rem = wg - s * nper;
    const int bm  = rem / nbn;
    const int bn  = rem - bm * nbn;
    const int row0 = bm * BM_;
    const int col0 = bn * BN_;

    const bf16* As = A  + (MODE == 1 ? (size_t)0 : (size_t)s * NT * 64);
    const bf16* Bs = BT + (size_t)s * NT * 64;

    const int tid = threadIdx.x;
    const int w = tid >> 6, l = tid & 63;
    const int wm = w >> 1;          // 0..1 -> rows wm*(BM_/2)
    const int wn = w & 1;           // 0..1 -> cols wn*(BN_/2)

    // staging lane constants (pre-swizzled source chunk; linear LDS dest)
    const int lr  = l >> 3;         // 0..7
    const int lch = (l & 7) ^ lr;
    // ds_read swizzled offsets (row&7 == l&7 for all reads below)
    const int l15 = l & 15;
    const int sw0 = (((l >> 4)    ) ^ (l & 7)) * 16;
    const int sw1 = (((l >> 4) + 4) ^ (l & 7)) * 16;

    auto stage = [&](int ts, int sb) {
        const bf16* ga = As + (size_t)(row0 + w * (BM_ / 4) + lr) * lda + ts * 64 + lch * 8;
        bf16* da = &lds[sb][(w * (BM_ / 4)) * 64];
#pragma unroll
        for (int j = 0; j < MFR; ++j)
            gload_lds16(ga + (size_t)(j * 8) * lda, da + j * 512);
        const bf16* gb = Bs + (size_t)(col0 + w * (BN_ / 4) + lr) * ldb + ts * 64 + lch * 8;
        bf16* db = &lds[sb][AELEMS + (w * (BN_ / 4)) * 64];
#pragma unroll
        for (int j = 0; j < NF; ++j)
            gload_lds16(gb + (size_t)(j * 8) * ldb, db + j * 512);
    };

    f32x4 acc[MFR][NF] = {};

    stage(0, 0);
    VMCNT0();
    BAR();

    for (int t = 0; t < NT; ++t) {
        const int sb = t & 1;
        if (t + 1 < NT) stage(t + 1, sb ^ 1);   // issue next-tile loads FIRST
        const char* Ab = (const char*)&lds[sb][0];
        const char* Bb = (const char*)&lds[sb][AELEMS];
        bf16x8 af[MFR][2], bfr[NF][2];
#pragma unroll
        for (int m = 0; m < MFR; ++m) {
            const char* p = Ab + (wm * (BM_ / 2) + m * 16 + l15) * 128;
            af[m][0] = *(const bf16x8*)(p + sw0);
            af[m][1] = *(const bf16x8*)(p + sw1);
        }
#pragma unroll
        for (int n = 0; n < NF; ++n) {
            const char* p = Bb + (wn * (BN_ / 2) + n * 16 + l15) * 128;
            bfr[n][0] = *(const bf16x8*)(p + sw0);
            bfr[n][1] = *(const bf16x8*)(p + sw1);
        }
#pragma unroll
        for (int m = 0; m < MFR; ++m)
#pragma unroll
            for (int n = 0; n < NF; ++n)
#pragma unroll
                for (int kk = 0; kk < 2; ++kk)
                    acc[m][n] = __builtin_amdgcn_mfma_f32_16x16x32_bf16(
                        af[m][kk], bfr[n][kk], acc[m][n], 0, 0, 0);
        VMCNT0();
        BAR();
    }

    // epilogue. C/D: col=lane&15, row=(lane>>4)*4+q
    const int crow = (l >> 4) * 4;
    char* outBase = (char*)Cout + (size_t)s * mrows * ldc * (OUT_BF16 ? 2 : 4);
    const float* htp = (MODE == 2) ? hh + (size_t)128 * FFN : nullptr;
#pragma unroll
    for (int m = 0; m < MFR; ++m) {
        int row = row0 + wm * (BM_ / 2) + m * 16 + crow;
#pragma unroll
        for (int n = 0; n < NF; ++n) {
            int col = col0 + wn * (BN_ / 2) + n * 16 + l15;
            float bv = ADD_BIAS ? bias[col] : 0.f;
#pragma unroll
            for (int q = 0; q < 4; ++q) {
                int r = row + q;
                float v = acc[m][n][q] + bv;
                if (MODE == 2) {
                    int bq = r >> 10;
                    int ih = bq * 32 + ((r >> 5) & 31);
                    int jt = bq * 32 + (r & 31);
                    v += hh[(size_t)ih * FFN + col] + htp[(size_t)jt * FFN + col];
                }
                if (RELU) v = fmaxf(v, 0.f);
                size_t idx = (size_t)r * ldc + col;
                if (OUT_BF16)
                    ((bf16*)outBase)[idx] = __float2bfloat16(v);
                else
                    ((float*)outBase)[idx] = v;
            }
        }
    }
}

// ---------------------------------------------------------------------------
extern "C" void kernel_launch(void* const* d_in, const int* in_sizes, int n_in,
                              void* d_out, int out_size, void* d_ws, size_t ws_size,
                              hipStream_t stream)
{
    const float* cand = (const float*)d_in[0];
    const float* tok  = (const float*)d_in[1];
    const float* W1   = (const float*)d_in[2];
    const float* b1   = (const float*)d_in[3];
    const float* W2   = (const float*)d_in[4];
    const float* b2   = (const float*)d_in[5];
    const int*   ids  = (const int*)d_in[6];
    float* out = (float*)d_out;

    char* ws = (char*)d_ws;
    const size_t ctx_sz  = (size_t)M_PAIRS * HH * 2;        //  4,194,304
    const size_t cnd_sz  = (size_t)BB * KK * HH * 2;        //    131,072
    const size_t w1t_sz  = (size_t)FFN * K1 * 2;            //  7,077,888
    const size_t w2t_sz  = (size_t)HH * FFN * 2;            //  2,359,296
    const size_t hht_sz  = (size_t)2 * 128 * FFN * 4;       //  2,359,296
    bf16*  ctxB  = (bf16*)ws;
    bf16*  candB = (bf16*)(ws + ctx_sz);
    bf16*  W1T   = (bf16*)(ws + ctx_sz + cnd_sz);
    bf16*  W2T   = (bf16*)(ws + ctx_sz + cnd_sz + w1t_sz);
    float* HhHt  = (float*)(ws + ctx_sz + cnd_sz + w1t_sz + w2t_sz);
    char* regionX = ws + ctx_sz + cnd_sz + w1t_sz + w2t_sz + hht_sz;
    bf16* tbl = (bf16*)regionX;   // 16 MB, dead after build_ctx
    bf16* hid = (bf16*)regionX;   // 18.9 MB, written by gemm1c afterwards

    // 1) weight transposes + cand bf16 cast (one kernel)
    transpose_both<<<W1_TILES + W2_TILES + CAND_BLKS, 256, 0, stream>>>(
        W1, W1T, W2, W2T, cand, candB);

    // 2) sparse range-max tables: l0+l1 fused, then l2+l3 fused
    build_table_A<<<BB * SS, 256, 0, stream>>>(
        tok, tbl + 0 * TBL_LVL_STRIDE, tbl + 1 * TBL_LVL_STRIDE);
    build_table_B<<<BB * SS, 256, 0, stream>>>(
        tbl + 1 * TBL_LVL_STRIDE, tbl + 2 * TBL_LVL_STRIDE,
        tbl + 3 * TBL_LVL_STRIDE);

    // 3) GEMM1a: Hh = candB @ W1T[:,0:512]^T, Ht = candB @ W1T[:,512:1024]^T.
    //    M=128, N=2304, K=512 (NT=8). One grid 2x24 = 48 blocks (s picks half).
    gemm_2ph<128, 96, false, false, false, 1><<<48, 256, 0, stream>>>(
        candB, W1T, nullptr, nullptr, HhHt,
        HH, K1, /*NT=*/8, /*nbn=*/24, /*nper=*/24, FFN, /*mrows=*/128);

    // 4) build ctx rows only (wave-per-pair, 16B loads/stores)
    build_ctx<<<M_PAIRS / 4, 256, 0, stream>>>(cand, tok, ids, tbl, ctxB);

    // 5) GEMM1c: hid = relu(ctxB @ W1T[:,1024:1536]^T + Hh[i] + Ht[j] + b1).
    //    64x96 tiles, grid 64x24 = 1536 = exactly 6 blocks/CU (3 rounds of 2).
    gemm_2ph<64, 96, true, true, true, 2><<<1536, 256, 0, stream>>>(
        ctxB, W1T + 1024, b1, HhHt, hid,
        HH, K1, /*NT=*/8, /*nbn=*/24, /*nper=*/1536, FFN, /*mrows=*/0);

    // 6) out = hid @ W2 + b2 -> f32 directly. 64x64 tiles, grid 64x8 = 512
    //    = 2 blocks/CU co-resident (drain hiding), NT=36.
    gemm_2ph<64, 64, false, false, true, 0><<<512, 256, 0, stream>>>(
        hid, W2T, b2, nullptr, out,
        FFN, FFN, /*NT=*/36, /*nbn=*/8, /*nper=*/512, HH, /*mrows=*/0);
}

// Round 11
// 73.152 us; speedup vs baseline: 2.1026x; 1.0732x over previous
//
#include <hip/hip_runtime.h>
#include <hip/hip_bf16.h>
#include <cstdint>

// Problem constants (reference: B=4, K=32, S=1024, H=512, FFN=2304)
#define BB 4
#define KK 32
#define SS 1024
#define HH 512
#define FFN 2304
#define M_PAIRS (BB * KK * KK)   // 4096
#define K1 (3 * HH)              // 1536

using bf16 = __hip_bfloat16;
using f32x4 = __attribute__((ext_vector_type(4))) float;
using bf16x8 = __attribute__((ext_vector_type(8))) short;

struct bf16x2 { bf16 x, y; };

__device__ __forceinline__ float bf2f(bf16 v) { return __bfloat162float(v); }
__device__ __forceinline__ float b2fr(short s) {
    unsigned u = ((unsigned)(unsigned short)s) << 16;
    float f; __builtin_memcpy(&f, &u, 4); return f;
}
__device__ __forceinline__ short f2br(float f) {
    bf16 h = __float2bfloat16(f);
    short s; __builtin_memcpy(&s, &h, 2); return s;
}

#define TBL_LVL_STRIDE ((size_t)BB * SS * HH)

#define W1_TILES (72 * 48)     // (2304/32) x (1536/32)
#define W2_TILES (16 * 72)     // (512/32)  x (2304/32)
#define CAND_BLKS 128          // 128*512 elems / (256 thr * 2)
#define PRE_TT (W1_TILES + W2_TILES + CAND_BLKS)   // 4736

// ---------------------------------------------------------------------------
// fused_pre: blocks [0, PRE_TT): weight transposes + cand cast.
//            blocks [PRE_TT, PRE_TT+4096): table_A (l0 q=4, l1 q=16 from tok).
// Independent inputs -> safe to co-schedule in one dispatch.
// ---------------------------------------------------------------------------
__global__ __launch_bounds__(256) void fused_pre(
    const float* __restrict__ W1, bf16* __restrict__ W1T,
    const float* __restrict__ W2, bf16* __restrict__ W2T,
    const float* __restrict__ cand, bf16* __restrict__ candB,
    const float* __restrict__ tok, bf16* __restrict__ tbl0,
    bf16* __restrict__ tbl1)
{
    int bid = blockIdx.x;
    if (bid >= PRE_TT) {                    // ---- table_A ----
        int tb = bid - PRE_TT;
        int bt = ((tb & 7) << 9) + (tb >> 3);
        int b = bt >> 10, t = bt & 1023;
        int h0 = threadIdx.x * 2;
        const float* base = tok + (size_t)b * SS * HH;
        float m0 = -INFINITY, m1 = -INFINITY;
        float l00 = 0.f, l01 = 0.f;
#pragma unroll
        for (int j = 0; j < 16; ++j) {
            int tt = min(t + j, SS - 1);
            float2 v = *(const float2*)(base + (size_t)tt * HH + h0);
            m0 = fmaxf(m0, v.x);
            m1 = fmaxf(m1, v.y);
            if (j == 3) { l00 = m0; l01 = m1; }
        }
        bf16x2 o;
        o.x = __float2bfloat16(l00);
        o.y = __float2bfloat16(l01);
        *(bf16x2*)(tbl0 + (size_t)bt * HH + h0) = o;
        o.x = __float2bfloat16(m0);
        o.y = __float2bfloat16(m1);
        *(bf16x2*)(tbl1 + (size_t)bt * HH + h0) = o;
        return;
    }
    if (bid >= W1_TILES + W2_TILES) {       // ---- cand f32 -> bf16 ----
        int idx = ((bid - W1_TILES - W2_TILES) * 256 + threadIdx.x) * 2;
        float2 v = *(const float2*)(cand + idx);
        bf16x2 o;
        o.x = __float2bfloat16(v.x);
        o.y = __float2bfloat16(v.y);
        *(bf16x2*)(candB + idx) = o;
        return;
    }
    __shared__ float tile[32][33];          // ---- transposes ----
    const float* in; bf16* out; int R, C, bx, by;
    if (bid < W1_TILES) {
        in = W1; out = W1T; R = K1; C = FFN;
        bx = bid % 72; by = bid / 72;
    } else {
        bid -= W1_TILES;
        in = W2; out = W2T; R = FFN; C = HH;
        bx = bid % 16; by = bid / 16;
    }
    int bc = bx * 32, br = by * 32;
    int tx = threadIdx.x & 31;
    int ty = threadIdx.x >> 5;
#pragma unroll
    for (int i = 0; i < 32; i += 8)
        tile[ty + i][tx] = in[(size_t)(br + ty + i) * C + bc + tx];
    __syncthreads();
#pragma unroll
    for (int i = 0; i < 32; i += 8)
        out[(size_t)(bc + ty + i) * R + br + tx] = __float2bfloat16(tile[tx][ty + i]);
}

// ---------------------------------------------------------------------------
__device__ __forceinline__ void gload_lds16(const bf16* g, bf16* l)
{
    __builtin_amdgcn_global_load_lds(
        (const __attribute__((address_space(1))) unsigned int*)g,
        (__attribute__((address_space(3))) unsigned int*)l,
        16, 0, 0);
}

#define BAR() asm volatile("s_barrier" ::: "memory")
#define VMCNT0() asm volatile("s_waitcnt vmcnt(0)" ::: "memory")

// ---------------------------------------------------------------------------
// gemm_2ph body (champion structure, generalized BM_): BM_ x BN_ tile, BK=64,
// 4 waves (2Mx2N), double-buffered LDS, vmcnt(0)+barrier per tile (>=2
// blocks/CU co-residency hides the drain), 16B-chunk XOR swizzle both sides,
// chunked XCD swizzle (bijective: nwg % 8 == 0).
// MODE 0: standard.  MODE 1: B-only split (s -> k-offset + out-row block).
// MODE 2: +HT epilogue: v = acc + b1[col] + Hh[b*32+i][col] + Ht[b*32+j][col].
// ---------------------------------------------------------------------------
template <int BM_, int BN_, bool RELU, bool OUT_BF16, bool ADD_BIAS, int MODE>
__device__ __forceinline__ void gemm_2ph_body(
    const bf16* __restrict__ A, const bf16* __restrict__ BT,
    const float* __restrict__ bias, const float* __restrict__ hh,
    void* __restrict__ Cout,
    int lda, int ldb, int NT, int nbn, int nper, int ldc, int mrows,
    int bid, int nwg)
{
    constexpr int MFR = BM_ / 32;            // m-frags per wave
    constexpr int NF  = BN_ / 32;            // n-frags per wave
    constexpr int AELEMS = BM_ * 64;
    constexpr int TILE_E = (BM_ + BN_) * 64;
    __shared__ __align__(16) bf16 lds[2][TILE_E];

    const int cpx = nwg >> 3;
    const int wg = (bid & 7) * cpx + (bid >> 3);

    const int s   = wg / nper;
    const int rem = wg - s * nper;
    const int bm  = rem / nbn;
    const int bn  = rem - bm * nbn;
    const int row0 = bm * BM_;
    const int col0 = bn * BN_;

    const bf16* As = A  + (MODE == 1 ? (size_t)0 : (size_t)s * NT * 64);
    const bf16* Bs = BT + (size_t)s * NT * 64;

    const int tid = threadIdx.x;
    const int w = tid >> 6, l = tid & 63;
    const int wm = w >> 1;          // 0..1 -> rows wm*(BM_/2)
    const int wn = w & 1;           // 0..1 -> cols wn*(BN_/2)

    const int lr  = l >> 3;         // 0..7
    const int lch = (l & 7) ^ lr;
    const int l15 = l & 15;
    const int sw0 = (((l >> 4)    ) ^ (l & 7)) * 16;
    const int sw1 = (((l >> 4) + 4) ^ (l & 7)) * 16;

    auto stage = [&](int ts, int sb) {
        const bf16* ga = As + (size_t)(row0 + w * (BM_ / 4) + lr) * lda + ts * 64 + lch * 8;
        bf16* da = &lds[sb][(w * (BM_ / 4)) * 64];
#pragma unroll
        for (int j = 0; j < MFR; ++j)
            gload_lds16(ga + (size_t)(j * 8) * lda, da + j * 512);
        const bf16* gb = Bs + (size_t)(col0 + w * (BN_ / 4) + lr) * ldb + ts * 64 + lch * 8;
        bf16* db = &lds[sb][AELEMS + (w * (BN_ / 4)) * 64];
#pragma unroll
        for (int j = 0; j < NF; ++j)
            gload_lds16(gb + (size_t)(j * 8) * ldb, db + j * 512);
    };

    f32x4 acc[MFR][NF] = {};

    stage(0, 0);
    VMCNT0();
    BAR();

    for (int t = 0; t < NT; ++t) {
        const int sb = t & 1;
        if (t + 1 < NT) stage(t + 1, sb ^ 1);   // issue next-tile loads FIRST
        const char* Ab = (const char*)&lds[sb][0];
        const char* Bb = (const char*)&lds[sb][AELEMS];
        bf16x8 af[MFR][2], bfr[NF][2];
#pragma unroll
        for (int m = 0; m < MFR; ++m) {
            const char* p = Ab + (wm * (BM_ / 2) + m * 16 + l15) * 128;
            af[m][0] = *(const bf16x8*)(p + sw0);
            af[m][1] = *(const bf16x8*)(p + sw1);
        }
#pragma unroll
        for (int n = 0; n < NF; ++n) {
            const char* p = Bb + (wn * (BN_ / 2) + n * 16 + l15) * 128;
            bfr[n][0] = *(const bf16x8*)(p + sw0);
            bfr[n][1] = *(const bf16x8*)(p + sw1);
        }
#pragma unroll
        for (int m = 0; m < MFR; ++m)
#pragma unroll
            for (int n = 0; n < NF; ++n)
#pragma unroll
                for (int kk = 0; kk < 2; ++kk)
                    acc[m][n] = __builtin_amdgcn_mfma_f32_16x16x32_bf16(
                        af[m][kk], bfr[n][kk], acc[m][n], 0, 0, 0);
        VMCNT0();
        BAR();
    }

    // epilogue. C/D: col=lane&15, row=(lane>>4)*4+q
    const int crow = (l >> 4) * 4;
    char* outBase = (char*)Cout + (size_t)s * mrows * ldc * (OUT_BF16 ? 2 : 4);
    const float* htp = (MODE == 2) ? hh + (size_t)128 * FFN : nullptr;
#pragma unroll
    for (int m = 0; m < MFR; ++m) {
        int row = row0 + wm * (BM_ / 2) + m * 16 + crow;
#pragma unroll
        for (int n = 0; n < NF; ++n) {
            int col = col0 + wn * (BN_ / 2) + n * 16 + l15;
            float bv = ADD_BIAS ? bias[col] : 0.f;
#pragma unroll
            for (int q = 0; q < 4; ++q) {
                int r = row + q;
                float v = acc[m][n][q] + bv;
                if (MODE == 2) {
                    int bq = r >> 10;
                    int ih = bq * 32 + ((r >> 5) & 31);
                    int jt = bq * 32 + (r & 31);
                    v += hh[(size_t)ih * FFN + col] + htp[(size_t)jt * FFN + col];
                }
                if (RELU) v = fmaxf(v, 0.f);
                size_t idx = (size_t)r * ldc + col;
                if (OUT_BF16)
                    ((bf16*)outBase)[idx] = __float2bfloat16(v);
                else
                    ((float*)outBase)[idx] = v;
            }
        }
    }
}

// ---------------------------------------------------------------------------
// fused_mid: blocks [0,48): gemm1a (Hh/Ht = candB @ W1T k-halves, MODE 1).
//            blocks [48, 48+4096): table_B (l2 q=64, l3 q=256 from l1).
// Both depend only on fused_pre -> safe in one dispatch.
// ---------------------------------------------------------------------------
__global__ __launch_bounds__(256, 2) void fused_mid(
    const bf16* __restrict__ candB, const bf16* __restrict__ W1T,
    float* __restrict__ HhHt,
    const bf16* __restrict__ tbl1, bf16* __restrict__ tbl2,
    bf16* __restrict__ tbl3)
{
    if (blockIdx.x < 48) {
        gemm_2ph_body<128, 96, false, false, false, 1>(
            candB, W1T, nullptr, nullptr, HhHt,
            HH, K1, /*NT=*/8, /*nbn=*/24, /*nper=*/24, FFN, /*mrows=*/128,
            blockIdx.x, 48);
        return;
    }
    int tb = blockIdx.x - 48;
    int bt = ((tb & 7) << 9) + (tb >> 3);
    int b = bt >> 10, t = bt & 1023;
    int h0 = threadIdx.x * 2;
    const bf16* base = tbl1 + (size_t)b * SS * HH;
    float m0 = -INFINITY, m1 = -INFINITY;
    float l20 = 0.f, l21 = 0.f;
#pragma unroll
    for (int j = 0; j < 16; ++j) {
        int tt = min(t + j * 16, SS - 16);
        bf16x2 v = *(const bf16x2*)(base + (size_t)tt * HH + h0);
        m0 = fmaxf(m0, bf2f(v.x));
        m1 = fmaxf(m1, bf2f(v.y));
        if (j == 3) { l20 = m0; l21 = m1; }
    }
    bf16x2 o;
    o.x = __float2bfloat16(l20);
    o.y = __float2bfloat16(l21);
    *(bf16x2*)(tbl2 + (size_t)bt * HH + h0) = o;
    o.x = __float2bfloat16(m0);
    o.y = __float2bfloat16(m1);
    *(bf16x2*)(tbl3 + (size_t)bt * HH + h0) = o;
}

// ---------------------------------------------------------------------------
// build_ctx: ONE WAVE per pair (4 pairs/block). Lane l owns 8 elems (16B).
// ---------------------------------------------------------------------------
__global__ __launch_bounds__(256) void build_ctx(
    const float* __restrict__ cand,
    const float* __restrict__ tok,
    const int* __restrict__ ids,
    const bf16* __restrict__ tbl,
    bf16* __restrict__ ctxB)          // [M_PAIRS][512]
{
    int w = threadIdx.x >> 6, l = threadIdx.x & 63;
    int pair = blockIdx.x * 4 + w;
    int b = pair >> 10;
    int i = (pair >> 5) & 31;
    int j = pair & 31;
    int h0 = l * 8;

    int si = ids[((b * KK + i) << 1)];
    int ei = ids[((b * KK + i) << 1) + 1];
    int sj = ids[((b * KK + j) << 1)];
    int ej = ids[((b * KK + j) << 1) + 1];
    int me = min(ei, ej);
    int ms = max(si, sj);

    float m[8];
    bf16x8 o;
    if (me < ms) {
        int L = ms - me;
#pragma unroll
        for (int e = 0; e < 8; ++e) m[e] = -INFINITY;
        if (L < 4) {
            const float* tb = tok + (size_t)b * SS * HH + h0;
            for (int tt = me; tt < ms; ++tt) {
                float4 v0 = *(const float4*)(tb + (size_t)tt * HH);
                float4 v1 = *(const float4*)(tb + (size_t)tt * HH + 4);
                m[0] = fmaxf(m[0], v0.x); m[1] = fmaxf(m[1], v0.y);
                m[2] = fmaxf(m[2], v0.z); m[3] = fmaxf(m[3], v0.w);
                m[4] = fmaxf(m[4], v1.x); m[5] = fmaxf(m[5], v1.y);
                m[6] = fmaxf(m[6], v1.z); m[7] = fmaxf(m[7], v1.w);
            }
        } else {
            int lvl = (L < 16) ? 0 : (L < 64) ? 1 : (L < 256) ? 2 : 3;
            int q = 4 << (2 * lvl);
            const bf16* base = tbl + (size_t)lvl * TBL_LVL_STRIDE
                               + (size_t)b * SS * HH + h0;
#pragma unroll
            for (int jj = 0; jj < 4; ++jj) {
                int p = min(me + jj * q, ms - q);
                bf16x8 v = *(const bf16x8*)(base + (size_t)p * HH);
#pragma unroll
                for (int e = 0; e < 8; ++e)
                    m[e] = fmaxf(m[e], b2fr(v[e]));
            }
        }
#pragma unroll
        for (int e = 0; e < 8; ++e) o[e] = f2br(m[e]);
    } else {
        const float* hp = cand + ((size_t)b * KK + i) * HH + h0;
        float4 v0 = *(const float4*)hp;
        float4 v1 = *(const float4*)(hp + 4);
        o[0] = f2br(v0.x); o[1] = f2br(v0.y); o[2] = f2br(v0.z); o[3] = f2br(v0.w);
        o[4] = f2br(v1.x); o[5] = f2br(v1.y); o[6] = f2br(v1.z); o[7] = f2br(v1.w);
    }
    *(bf16x8*)(ctxB + (size_t)pair * HH + h0) = o;
}

// ---------------------------------------------------------------------------
template <int BM_, int BN_, bool RELU, bool OUT_BF16, bool ADD_BIAS, int MODE>
__global__ __launch_bounds__(256, 2) void gemm_2ph(
    const bf16* __restrict__ A, const bf16* __restrict__ BT,
    const float* __restrict__ bias, const float* __restrict__ hh,
    void* __restrict__ Cout,
    int lda, int ldb, int NT, int nbn, int nper, int ldc, int mrows)
{
    gemm_2ph_body<BM_, BN_, RELU, OUT_BF16, ADD_BIAS, MODE>(
        A, BT, bias, hh, Cout, lda, ldb, NT, nbn, nper, ldc, mrows,
        blockIdx.x, gridDim.x);
}

// ---------------------------------------------------------------------------
extern "C" void kernel_launch(void* const* d_in, const int* in_sizes, int n_in,
                              void* d_out, int out_size, void* d_ws, size_t ws_size,
                              hipStream_t stream)
{
    const float* cand = (const float*)d_in[0];
    const float* tok  = (const float*)d_in[1];
    const float* W1   = (const float*)d_in[2];
    const float* b1   = (const float*)d_in[3];
    const float* W2   = (const float*)d_in[4];
    const float* b2   = (const float*)d_in[5];
    const int*   ids  = (const int*)d_in[6];
    float* out = (float*)d_out;

    char* ws = (char*)d_ws;
    const size_t ctx_sz  = (size_t)M_PAIRS * HH * 2;        //  4,194,304
    const size_t cnd_sz  = (size_t)BB * KK * HH * 2;        //    131,072
    const size_t w1t_sz  = (size_t)FFN * K1 * 2;            //  7,077,888
    const size_t w2t_sz  = (size_t)HH * FFN * 2;            //  2,359,296
    const size_t hht_sz  = (size_t)2 * 128 * FFN * 4;       //  2,359,296
    bf16*  ctxB  = (bf16*)ws;
    bf16*  candB = (bf16*)(ws + ctx_sz);
    bf16*  W1T   = (bf16*)(ws + ctx_sz + cnd_sz);
    bf16*  W2T   = (bf16*)(ws + ctx_sz + cnd_sz + w1t_sz);
    float* HhHt  = (float*)(ws + ctx_sz + cnd_sz + w1t_sz + w2t_sz);
    char* regionX = ws + ctx_sz + cnd_sz + w1t_sz + w2t_sz + hht_sz;
    bf16* tbl = (bf16*)regionX;   // 16 MB, dead after build_ctx
    bf16* hid = (bf16*)regionX;   // 18.9 MB, written by gemm1c afterwards

    // D1) transposes + cand cast + table l0/l1 (independent inputs, one dispatch)
    fused_pre<<<PRE_TT + BB * SS, 256, 0, stream>>>(
        W1, W1T, W2, W2T, cand, candB, tok,
        tbl + 0 * TBL_LVL_STRIDE, tbl + 1 * TBL_LVL_STRIDE);

    // D2) gemm1a (Hh/Ht) + table l2/l3 (both depend only on D1)
    fused_mid<<<48 + BB * SS, 256, 0, stream>>>(
        candB, W1T, HhHt,
        tbl + 1 * TBL_LVL_STRIDE, tbl + 2 * TBL_LVL_STRIDE,
        tbl + 3 * TBL_LVL_STRIDE);

    // D3) build ctx rows (wave-per-pair)
    build_ctx<<<M_PAIRS / 4, 256, 0, stream>>>(cand, tok, ids, tbl, ctxB);

    // D4) gemm1c: hid = relu(ctxB @ W1c^T + Hh[i] + Ht[j] + b1).
    //     64x96 tiles, grid 64x24 = 1536 = exactly 6 blocks/CU.
    gemm_2ph<64, 96, true, true, true, 2><<<1536, 256, 0, stream>>>(
        ctxB, W1T + 1024, b1, HhHt, hid,
        HH, K1, /*NT=*/8, /*nbn=*/24, /*nper=*/1536, FFN, /*mrows=*/0);

    // D5) out = hid @ W2 + b2 -> f32. 64x64 tiles, grid 64x8 = 512 = 2/CU.
    gemm_2ph<64, 64, false, false, true, 0><<<512, 256, 0, stream>>>(
        hid, W2T, b2, nullptr, out,
        FFN, FFN, /*NT=*/36, /*nbn=*/8, /*nper=*/512, HH, /*mrows=*/0);
}

// Round 12
// 67.427 us; speedup vs baseline: 2.2811x; 1.0849x over previous
//
#include <hip/hip_runtime.h>
#include <hip/hip_bf16.h>
#include <cstdint>

// Problem constants (reference: B=4, K=32, S=1024, H=512, FFN=2304)
#define BB 4
#define KK 32
#define SS 1024
#define HH 512
#define FFN 2304
#define M_PAIRS (BB * KK * KK)   // 4096
#define K1 (3 * HH)              // 1536

using bf16 = __hip_bfloat16;
using f32x4 = __attribute__((ext_vector_type(4))) float;
using bf16x8 = __attribute__((ext_vector_type(8))) short;

struct bf16x2 { bf16 x, y; };

__device__ __forceinline__ float bf2f(bf16 v) { return __bfloat162float(v); }
__device__ __forceinline__ float b2fr(short s) {
    unsigned u = ((unsigned)(unsigned short)s) << 16;
    float f; __builtin_memcpy(&f, &u, 4); return f;
}
__device__ __forceinline__ short f2br(float f) {
    bf16 h = __float2bfloat16(f);
    short s; __builtin_memcpy(&s, &h, 2); return s;
}

#define TBL_LVL_STRIDE ((size_t)BB * SS * HH)

// D1 block ranges
#define TA_BLKS 512            // tableA: 4 b x 16 t-chunks x 8 h-chunks
#define T1_BLKS (36 * 24)      // W1T 64x64 tiles (C/64 x R/64) = 864
#define T2_BLKS (8 * 36)       // W2T tiles = 288
#define CAND_BLKS 128          // 128*512 / (256*2)
#define PRE_TOTAL (TA_BLKS + T1_BLKS + T2_BLKS + CAND_BLKS)   // 1792

// ---------------------------------------------------------------------------
// fused_pre (D1):
//  [0, TA_BLKS): block-local table_A -- stage 80-row tok window in LDS once,
//    l0 (q=4) from window, l1 (q=16) from LDS l0: l1[t]=max_j<4 l0[t+4j].
//    Exact vs direct 16-read form for ALL t (for t>S-16 both equal
//    max tok[t..S) via row clamping); bf16 round is monotone -> bit-exact.
//  [TA, +T1+T2): 64x64 transposes, bf16x8 (16B) writes = 128B/wave segments.
//  tail: cand f32 -> bf16 cast.
// ---------------------------------------------------------------------------
__global__ __launch_bounds__(256) void fused_pre(
    const float* __restrict__ W1, bf16* __restrict__ W1T,
    const float* __restrict__ W2, bf16* __restrict__ W2T,
    const float* __restrict__ cand, bf16* __restrict__ candB,
    const float* __restrict__ tok, bf16* __restrict__ tbl0,
    bf16* __restrict__ tbl1)
{
    __shared__ __align__(16) char buf[30720];
    int bid = blockIdx.x;
    int tid = threadIdx.x;

    if (bid < TA_BLKS) {                    // ---- block-local table_A ----
        int hb = bid & 7;                   // h-chunk
        int tc = (bid >> 3) & 15;           // t-chunk
        int b  = bid >> 7;
        int T = tc * 64, H0 = hb * 64;
        float (*tw)[64] = (float(*)[64])buf;              // [80][64] f32
        bf16 (*l0s)[64] = (bf16(*)[64])(buf + 80 * 64 * 4); // [80][64] bf16
        int l = tid & 63, w = tid >> 6;
        const float* tp = tok + (size_t)b * SS * HH + H0 + l;
#pragma unroll
        for (int i = 0; i < 20; ++i) {      // 80 clamped rows
            int r = w + i * 4;
            tw[r][l] = tp[(size_t)min(T + r, SS - 1) * HH];
        }
        __syncthreads();
#pragma unroll
        for (int i = 0; i < 19; ++i) {      // l0 rows 0..75
            int r = w + i * 4;
            float m = fmaxf(fmaxf(tw[r][l], tw[r + 1][l]),
                            fmaxf(tw[r + 2][l], tw[r + 3][l]));
            l0s[r][l] = __float2bfloat16(m);
            if (r < 64)
                tbl0[((size_t)b * SS + T + r) * HH + H0 + l] = __float2bfloat16(m);
        }
        __syncthreads();
#pragma unroll
        for (int i = 0; i < 16; ++i) {      // l1 rows 0..63
            int r = w + i * 4;
            float m = fmaxf(fmaxf(bf2f(l0s[r][l]), bf2f(l0s[r + 4][l])),
                            fmaxf(bf2f(l0s[r + 8][l]), bf2f(l0s[r + 12][l])));
            tbl1[((size_t)b * SS + T + r) * HH + H0 + l] = __float2bfloat16(m);
        }
        return;
    }
    bid -= TA_BLKS;
    if (bid >= T1_BLKS + T2_BLKS) {         // ---- cand f32 -> bf16 ----
        int idx = ((bid - T1_BLKS - T2_BLKS) * 256 + tid) * 2;
        float2 v = *(const float2*)(cand + idx);
        bf16x2 o;
        o.x = __float2bfloat16(v.x);
        o.y = __float2bfloat16(v.y);
        *(bf16x2*)(candB + idx) = o;
        return;
    }
    // ---- 64x64 transpose: in[R][C] f32 -> out[C][R] bf16 ----
    const float* in; bf16* outp; int R, C, bx, by;
    if (bid < T1_BLKS) { in = W1; outp = W1T; R = K1; C = FFN; bx = bid % 36; by = bid / 36; }
    else { bid -= T1_BLKS; in = W2; outp = W2T; R = FFN; C = HH; bx = bid % 8; by = bid / 8; }
    int bc = bx * 64, br = by * 64;
    float (*tile)[65] = (float(*)[65])buf;  // [64][65] f32 = 16640 B
    int tx = tid & 63, tg = tid >> 6;
#pragma unroll
    for (int i = 0; i < 16; ++i) {
        int r = tg + i * 4;
        tile[r][tx] = in[(size_t)(br + r) * C + bc + tx];
    }
    __syncthreads();
    int c = tid >> 3, rc = (tid & 7) * 8;
#pragma unroll
    for (int p = 0; p < 2; ++p) {
        int cc = c + p * 32;
        bf16x8 o;
#pragma unroll
        for (int e = 0; e < 8; ++e) o[e] = f2br(tile[rc + e][cc]);
        *(bf16x8*)(outp + (size_t)(bc + cc) * R + br + rc) = o;
    }
}

// ---------------------------------------------------------------------------
__device__ __forceinline__ void gload_lds16(const bf16* g, bf16* l)
{
    __builtin_amdgcn_global_load_lds(
        (const __attribute__((address_space(1))) unsigned int*)g,
        (__attribute__((address_space(3))) unsigned int*)l,
        16, 0, 0);
}

#define BAR() asm volatile("s_barrier" ::: "memory")
#define VMCNT0() asm volatile("s_waitcnt vmcnt(0)" ::: "memory")

// ---------------------------------------------------------------------------
// gemm_2ph body (champion structure, generalized BM_): BM_ x BN_ tile, BK=64,
// 4 waves (2Mx2N), double-buffered LDS, vmcnt(0)+barrier per tile (>=2
// blocks/CU co-residency hides the drain), 16B-chunk XOR swizzle both sides,
// chunked XCD swizzle (bijective: nwg % 8 == 0).
// MODE 0: standard.  MODE 1: B-only split (s -> k-offset + out-row block).
// MODE 2: +HT epilogue: v = acc + b1[col] + Hh[b*32+i][col] + Ht[b*32+j][col].
// ---------------------------------------------------------------------------
template <int BM_, int BN_, bool RELU, bool OUT_BF16, bool ADD_BIAS, int MODE>
__device__ __forceinline__ void gemm_2ph_body(
    const bf16* __restrict__ A, const bf16* __restrict__ BT,
    const float* __restrict__ bias, const float* __restrict__ hh,
    void* __restrict__ Cout,
    int lda, int ldb, int NT, int nbn, int nper, int ldc, int mrows,
    int bid, int nwg)
{
    constexpr int MFR = BM_ / 32;            // m-frags per wave
    constexpr int NF  = BN_ / 32;            // n-frags per wave
    constexpr int AELEMS = BM_ * 64;
    constexpr int TILE_E = (BM_ + BN_) * 64;
    __shared__ __align__(16) bf16 lds[2][TILE_E];

    const int cpx = nwg >> 3;
    const int wg = (bid & 7) * cpx + (bid >> 3);

    const int s   = wg / nper;
    const int rem = wg - s * nper;
    const int bm  = rem / nbn;
    const int bn  = rem - bm * nbn;
    const int row0 = bm * BM_;
    const int col0 = bn * BN_;

    const bf16* As = A  + (MODE == 1 ? (size_t)0 : (size_t)s * NT * 64);
    const bf16* Bs = BT + (size_t)s * NT * 64;

    const int tid = threadIdx.x;
    const int w = tid >> 6, l = tid & 63;
    const int wm = w >> 1;          // 0..1 -> rows wm*(BM_/2)
    const int wn = w & 1;           // 0..1 -> cols wn*(BN_/2)

    const int lr  = l >> 3;         // 0..7
    const int lch = (l & 7) ^ lr;
    const int l15 = l & 15;
    const int sw0 = (((l >> 4)    ) ^ (l & 7)) * 16;
    const int sw1 = (((l >> 4) + 4) ^ (l & 7)) * 16;

    auto stage = [&](int ts, int sb) {
        const bf16* ga = As + (size_t)(row0 + w * (BM_ / 4) + lr) * lda + ts * 64 + lch * 8;
        bf16* da = &lds[sb][(w * (BM_ / 4)) * 64];
#pragma unroll
        for (int j = 0; j < MFR; ++j)
            gload_lds16(ga + (size_t)(j * 8) * lda, da + j * 512);
        const bf16* gb = Bs + (size_t)(col0 + w * (BN_ / 4) + lr) * ldb + ts * 64 + lch * 8;
        bf16* db = &lds[sb][AELEMS + (w * (BN_ / 4)) * 64];
#pragma unroll
        for (int j = 0; j < NF; ++j)
            gload_lds16(gb + (size_t)(j * 8) * ldb, db + j * 512);
    };

    f32x4 acc[MFR][NF] = {};

    stage(0, 0);
    VMCNT0();
    BAR();

    for (int t = 0; t < NT; ++t) {
        const int sb = t & 1;
        if (t + 1 < NT) stage(t + 1, sb ^ 1);   // issue next-tile loads FIRST
        const char* Ab = (const char*)&lds[sb][0];
        const char* Bb = (const char*)&lds[sb][AELEMS];
        bf16x8 af[MFR][2], bfr[NF][2];
#pragma unroll
        for (int m = 0; m < MFR; ++m) {
            const char* p = Ab + (wm * (BM_ / 2) + m * 16 + l15) * 128;
            af[m][0] = *(const bf16x8*)(p + sw0);
            af[m][1] = *(const bf16x8*)(p + sw1);
        }
#pragma unroll
        for (int n = 0; n < NF; ++n) {
            const char* p = Bb + (wn * (BN_ / 2) + n * 16 + l15) * 128;
            bfr[n][0] = *(const bf16x8*)(p + sw0);
            bfr[n][1] = *(const bf16x8*)(p + sw1);
        }
#pragma unroll
        for (int m = 0; m < MFR; ++m)
#pragma unroll
            for (int n = 0; n < NF; ++n)
#pragma unroll
                for (int kk = 0; kk < 2; ++kk)
                    acc[m][n] = __builtin_amdgcn_mfma_f32_16x16x32_bf16(
                        af[m][kk], bfr[n][kk], acc[m][n], 0, 0, 0);
        VMCNT0();
        BAR();
    }

    // epilogue. C/D: col=lane&15, row=(lane>>4)*4+q
    const int crow = (l >> 4) * 4;
    char* outBase = (char*)Cout + (size_t)s * mrows * ldc * (OUT_BF16 ? 2 : 4);
    const float* htp = (MODE == 2) ? hh + (size_t)128 * FFN : nullptr;
#pragma unroll
    for (int m = 0; m < MFR; ++m) {
        int row = row0 + wm * (BM_ / 2) + m * 16 + crow;
#pragma unroll
        for (int n = 0; n < NF; ++n) {
            int col = col0 + wn * (BN_ / 2) + n * 16 + l15;
            float bv = ADD_BIAS ? bias[col] : 0.f;
#pragma unroll
            for (int q = 0; q < 4; ++q) {
                int r = row + q;
                float v = acc[m][n][q] + bv;
                if (MODE == 2) {
                    int bq = r >> 10;
                    int ih = bq * 32 + ((r >> 5) & 31);
                    int jt = bq * 32 + (r & 31);
                    v += hh[(size_t)ih * FFN + col] + htp[(size_t)jt * FFN + col];
                }
                if (RELU) v = fmaxf(v, 0.f);
                size_t idx = (size_t)r * ldc + col;
                if (OUT_BF16)
                    ((bf16*)outBase)[idx] = __float2bfloat16(v);
                else
                    ((float*)outBase)[idx] = v;
            }
        }
    }
}

// ---------------------------------------------------------------------------
// fused_mid (D2): blocks [0,48): gemm1a (Hh/Ht = candB @ W1T k-halves, MODE 1).
//                 blocks [48, 48+4096): table_B (l2 q=64, l3 q=256 from l1).
// ---------------------------------------------------------------------------
__global__ __launch_bounds__(256, 2) void fused_mid(
    const bf16* __restrict__ candB, const bf16* __restrict__ W1T,
    float* __restrict__ HhHt,
    const bf16* __restrict__ tbl1, bf16* __restrict__ tbl2,
    bf16* __restrict__ tbl3)
{
    if (blockIdx.x < 48) {
        gemm_2ph_body<128, 96, false, false, false, 1>(
            candB, W1T, nullptr, nullptr, HhHt,
            HH, K1, /*NT=*/8, /*nbn=*/24, /*nper=*/24, FFN, /*mrows=*/128,
            blockIdx.x, 48);
        return;
    }
    int tb = blockIdx.x - 48;
    int bt = ((tb & 7) << 9) + (tb >> 3);
    int b = bt >> 10, t = bt & 1023;
    int h0 = threadIdx.x * 2;
    const bf16* base = tbl1 + (size_t)b * SS * HH;
    float m0 = -INFINITY, m1 = -INFINITY;
    float l20 = 0.f, l21 = 0.f;
#pragma unroll
    for (int j = 0; j < 16; ++j) {
        int tt = min(t + j * 16, SS - 16);
        bf16x2 v = *(const bf16x2*)(base + (size_t)tt * HH + h0);
        m0 = fmaxf(m0, bf2f(v.x));
        m1 = fmaxf(m1, bf2f(v.y));
        if (j == 3) { l20 = m0; l21 = m1; }
    }
    bf16x2 o;
    o.x = __float2bfloat16(l20);
    o.y = __float2bfloat16(l21);
    *(bf16x2*)(tbl2 + (size_t)bt * HH + h0) = o;
    o.x = __float2bfloat16(m0);
    o.y = __float2bfloat16(m1);
    *(bf16x2*)(tbl3 + (size_t)bt * HH + h0) = o;
}

// ---------------------------------------------------------------------------
// build_ctx (D3): ONE WAVE per pair (4 pairs/block). Lane l owns 8 elems.
// ---------------------------------------------------------------------------
__global__ __launch_bounds__(256) void build_ctx(
    const float* __restrict__ cand,
    const float* __restrict__ tok,
    const int* __restrict__ ids,
    const bf16* __restrict__ tbl,
    bf16* __restrict__ ctxB)          // [M_PAIRS][512]
{
    int w = threadIdx.x >> 6, l = threadIdx.x & 63;
    int pair = blockIdx.x * 4 + w;
    int b = pair >> 10;
    int i = (pair >> 5) & 31;
    int j = pair & 31;
    int h0 = l * 8;

    int si = ids[((b * KK + i) << 1)];
    int ei = ids[((b * KK + i) << 1) + 1];
    int sj = ids[((b * KK + j) << 1)];
    int ej = ids[((b * KK + j) << 1) + 1];
    int me = min(ei, ej);
    int ms = max(si, sj);

    float m[8];
    bf16x8 o;
    if (me < ms) {
        int L = ms - me;
#pragma unroll
        for (int e = 0; e < 8; ++e) m[e] = -INFINITY;
        if (L < 4) {
            const float* tb = tok + (size_t)b * SS * HH + h0;
            for (int tt = me; tt < ms; ++tt) {
                float4 v0 = *(const float4*)(tb + (size_t)tt * HH);
                float4 v1 = *(const float4*)(tb + (size_t)tt * HH + 4);
                m[0] = fmaxf(m[0], v0.x); m[1] = fmaxf(m[1], v0.y);
                m[2] = fmaxf(m[2], v0.z); m[3] = fmaxf(m[3], v0.w);
                m[4] = fmaxf(m[4], v1.x); m[5] = fmaxf(m[5], v1.y);
                m[6] = fmaxf(m[6], v1.z); m[7] = fmaxf(m[7], v1.w);
            }
        } else {
            int lvl = (L < 16) ? 0 : (L < 64) ? 1 : (L < 256) ? 2 : 3;
            int q = 4 << (2 * lvl);
            const bf16* base = tbl + (size_t)lvl * TBL_LVL_STRIDE
                               + (size_t)b * SS * HH + h0;
#pragma unroll
            for (int jj = 0; jj < 4; ++jj) {
                int p = min(me + jj * q, ms - q);
                bf16x8 v = *(const bf16x8*)(base + (size_t)p * HH);
#pragma unroll
                for (int e = 0; e < 8; ++e)
                    m[e] = fmaxf(m[e], b2fr(v[e]));
            }
        }
#pragma unroll
        for (int e = 0; e < 8; ++e) o[e] = f2br(m[e]);
    } else {
        const float* hp = cand + ((size_t)b * KK + i) * HH + h0;
        float4 v0 = *(const float4*)hp;
        float4 v1 = *(const float4*)(hp + 4);
        o[0] = f2br(v0.x); o[1] = f2br(v0.y); o[2] = f2br(v0.z); o[3] = f2br(v0.w);
        o[4] = f2br(v1.x); o[5] = f2br(v1.y); o[6] = f2br(v1.z); o[7] = f2br(v1.w);
    }
    *(bf16x8*)(ctxB + (size_t)pair * HH + h0) = o;
}

// ---------------------------------------------------------------------------
template <int BM_, int BN_, bool RELU, bool OUT_BF16, bool ADD_BIAS, int MODE>
__global__ __launch_bounds__(256, 2) void gemm_2ph(
    const bf16* __restrict__ A, const bf16* __restrict__ BT,
    const float* __restrict__ bias, const float* __restrict__ hh,
    void* __restrict__ Cout,
    int lda, int ldb, int NT, int nbn, int nper, int ldc, int mrows)
{
    gemm_2ph_body<BM_, BN_, RELU, OUT_BF16, ADD_BIAS, MODE>(
        A, BT, bias, hh, Cout, lda, ldb, NT, nbn, nper, ldc, mrows,
        blockIdx.x, gridDim.x);
}

// ---------------------------------------------------------------------------
extern "C" void kernel_launch(void* const* d_in, const int* in_sizes, int n_in,
                              void* d_out, int out_size, void* d_ws, size_t ws_size,
                              hipStream_t stream)
{
    const float* cand = (const float*)d_in[0];
    const float* tok  = (const float*)d_in[1];
    const float* W1   = (const float*)d_in[2];
    const float* b1   = (const float*)d_in[3];
    const float* W2   = (const float*)d_in[4];
    const float* b2   = (const float*)d_in[5];
    const int*   ids  = (const int*)d_in[6];
    float* out = (float*)d_out;

    char* ws = (char*)d_ws;
    const size_t ctx_sz  = (size_t)M_PAIRS * HH * 2;        //  4,194,304
    const size_t cnd_sz  = (size_t)BB * KK * HH * 2;        //    131,072
    const size_t w1t_sz  = (size_t)FFN * K1 * 2;            //  7,077,888
    const size_t w2t_sz  = (size_t)HH * FFN * 2;            //  2,359,296
    const size_t hht_sz  = (size_t)2 * 128 * FFN * 4;       //  2,359,296
    bf16*  ctxB  = (bf16*)ws;
    bf16*  candB = (bf16*)(ws + ctx_sz);
    bf16*  W1T   = (bf16*)(ws + ctx_sz + cnd_sz);
    bf16*  W2T   = (bf16*)(ws + ctx_sz + cnd_sz + w1t_sz);
    float* HhHt  = (float*)(ws + ctx_sz + cnd_sz + w1t_sz + w2t_sz);
    char* regionX = ws + ctx_sz + cnd_sz + w1t_sz + w2t_sz + hht_sz;
    bf16* tbl = (bf16*)regionX;   // 16 MB, dead after build_ctx
    bf16* hid = (bf16*)regionX;   // 18.9 MB, written by gemm1c afterwards

    // D1) block-local table l0/l1 + 64x64 transposes + cand cast
    fused_pre<<<PRE_TOTAL, 256, 0, stream>>>(
        W1, W1T, W2, W2T, cand, candB, tok,
        tbl + 0 * TBL_LVL_STRIDE, tbl + 1 * TBL_LVL_STRIDE);

    // D2) gemm1a (Hh/Ht) + table l2/l3 (both depend only on D1)
    fused_mid<<<48 + BB * SS, 256, 0, stream>>>(
        candB, W1T, HhHt,
        tbl + 1 * TBL_LVL_STRIDE, tbl + 2 * TBL_LVL_STRIDE,
        tbl + 3 * TBL_LVL_STRIDE);

    // D3) build ctx rows (wave-per-pair)
    build_ctx<<<M_PAIRS / 4, 256, 0, stream>>>(cand, tok, ids, tbl, ctxB);

    // D4) gemm1c: hid = relu(ctxB @ W1c^T + Hh[i] + Ht[j] + b1).
    //     64x96 tiles, grid 64x24 = 1536 = exactly 6 blocks/CU.
    gemm_2ph<64, 96, true, true, true, 2><<<1536, 256, 0, stream>>>(
        ctxB, W1T + 1024, b1, HhHt, hid,
        HH, K1, /*NT=*/8, /*nbn=*/24, /*nper=*/1536, FFN, /*mrows=*/0);

    // D5) out = hid @ W2 + b2 -> f32. 64x64 tiles, grid 64x8 = 512 = 2/CU.
    gemm_2ph<64, 64, false, false, true, 0><<<512, 256, 0, stream>>>(
        hid, W2T, b2, nullptr, out,
        FFN, FFN, /*NT=*/36, /*nbn=*/8, /*nper=*/512, HH, /*mrows=*/0);
}

// Round 13
// 67.180 us; speedup vs baseline: 2.2895x; 1.0037x over previous
//
#include <hip/hip_runtime.h>
#include <hip/hip_bf16.h>
#include <cstdint>

// Problem constants (reference: B=4, K=32, S=1024, H=512, FFN=2304)
#define BB 4
#define KK 32
#define SS 1024
#define HH 512
#define FFN 2304
#define M_PAIRS (BB * KK * KK)   // 4096
#define K1 (3 * HH)              // 1536

using bf16 = __hip_bfloat16;
using f32x4 = __attribute__((ext_vector_type(4))) float;
using bf16x8 = __attribute__((ext_vector_type(8))) short;

struct bf16x2 { bf16 x, y; };

__device__ __forceinline__ float bf2f(bf16 v) { return __bfloat162float(v); }
__device__ __forceinline__ float b2fr(short s) {
    unsigned u = ((unsigned)(unsigned short)s) << 16;
    float f; __builtin_memcpy(&f, &u, 4); return f;
}
__device__ __forceinline__ short f2br(float f) {
    bf16 h = __float2bfloat16(f);
    short s; __builtin_memcpy(&s, &h, 2); return s;
}

#define TBL_LVL_STRIDE ((size_t)BB * SS * HH)

// D1 block ranges
#define TA_BLKS 512            // tableAll: 4 b x 16 t-chunks x 8 h-chunks
#define T1_BLKS (36 * 24)      // W1T 64x64 tiles = 864
#define T2_BLKS (8 * 36)       // W2T tiles = 288
#define CAND_BLKS 128
#define PRE_TOTAL (TA_BLKS + T1_BLKS + T2_BLKS + CAND_BLKS)   // 1792

// ---------------------------------------------------------------------------
// fused_pre (D1):
//  [0, TA_BLKS): ALL-LEVEL table build (q = 4, 16, 64) in one block.
//    Window: 128 clamped tok rows (rows T+r, r<128, clamped at S-1).
//    l0[r] (r<124) = max tw[r..r+3];  l1[r] (r<112) = max l0[r+4j], j<4;
//    l2[r] (r<64)  = max l1[r+16j], j<4.  Dependency check: l2 needs l1<=111,
//    l1 needs l0<=123, l0 needs tok<=126 -- all in-window. Queried entries
//    (t <= S-q) are exact window maxima; bf16 round is monotone -> bit-exact.
//  [TA, +T1+T2): 64x64 transposes, bf16x8 writes.  tail: cand f32->bf16.
// ---------------------------------------------------------------------------
__global__ __launch_bounds__(256) void fused_pre(
    const float* __restrict__ W1, bf16* __restrict__ W1T,
    const float* __restrict__ W2, bf16* __restrict__ W2T,
    const float* __restrict__ cand, bf16* __restrict__ candB,
    const float* __restrict__ tok, bf16* __restrict__ tbl0,
    bf16* __restrict__ tbl1, bf16* __restrict__ tbl2)
{
    __shared__ __align__(16) char buf[65536];
    int bid = blockIdx.x;
    int tid = threadIdx.x;

    if (bid < TA_BLKS) {                    // ---- all-level table build ----
        int hb = bid & 7;                   // h-chunk
        int tc = (bid >> 3) & 15;           // t-chunk
        int b  = bid >> 7;
        int T = tc * 64, H0 = hb * 64;
        float (*tw)[64]  = (float(*)[64])buf;                 // [128][64] f32
        bf16 (*l0s)[64] = (bf16(*)[64])(buf + 32768);         // [128][64]
        bf16 (*l1s)[64] = (bf16(*)[64])(buf + 32768 + 16384); // [128][64]
        int l = tid & 63, w = tid >> 6;
        const float* tp = tok + (size_t)b * SS * HH + H0 + l;
#pragma unroll
        for (int i = 0; i < 32; ++i) {      // 128 clamped rows
            int r = w + i * 4;
            tw[r][l] = tp[(size_t)min(T + r, SS - 1) * HH];
        }
        __syncthreads();
#pragma unroll
        for (int i = 0; i < 31; ++i) {      // l0 rows 0..123
            int r = w + i * 4;
            l0s[r][l] = __float2bfloat16(
                fmaxf(fmaxf(tw[r][l], tw[r + 1][l]),
                      fmaxf(tw[r + 2][l], tw[r + 3][l])));
        }
        __syncthreads();
#pragma unroll
        for (int i = 0; i < 28; ++i) {      // l1 rows 0..111
            int r = w + i * 4;
            l1s[r][l] = __float2bfloat16(
                fmaxf(fmaxf(bf2f(l0s[r][l]), bf2f(l0s[r + 4][l])),
                      fmaxf(bf2f(l0s[r + 8][l]), bf2f(l0s[r + 12][l]))));
        }
        __syncthreads();
#pragma unroll
        for (int i = 0; i < 16; ++i) {      // l2 + writes, rows 0..63
            int r = w + i * 4;
            size_t o = ((size_t)b * SS + T + r) * HH + H0 + l;
            tbl0[o] = l0s[r][l];
            tbl1[o] = l1s[r][l];
            float m = fmaxf(fmaxf(bf2f(l1s[r][l]), bf2f(l1s[r + 16][l])),
                            fmaxf(bf2f(l1s[r + 32][l]), bf2f(l1s[r + 48][l])));
            tbl2[o] = __float2bfloat16(m);
        }
        return;
    }
    bid -= TA_BLKS;
    if (bid >= T1_BLKS + T2_BLKS) {         // ---- cand f32 -> bf16 ----
        int idx = ((bid - T1_BLKS - T2_BLKS) * 256 + tid) * 2;
        float2 v = *(const float2*)(cand + idx);
        bf16x2 o;
        o.x = __float2bfloat16(v.x);
        o.y = __float2bfloat16(v.y);
        *(bf16x2*)(candB + idx) = o;
        return;
    }
    // ---- 64x64 transpose: in[R][C] f32 -> out[C][R] bf16 ----
    const float* in; bf16* outp; int R, C, bx, by;
    if (bid < T1_BLKS) { in = W1; outp = W1T; R = K1; C = FFN; bx = bid % 36; by = bid / 36; }
    else { bid -= T1_BLKS; in = W2; outp = W2T; R = FFN; C = HH; bx = bid % 8; by = bid / 8; }
    int bc = bx * 64, br = by * 64;
    float (*tile)[65] = (float(*)[65])buf;  // [64][65] f32
    int tx = tid & 63, tg = tid >> 6;
#pragma unroll
    for (int i = 0; i < 16; ++i) {
        int r = tg + i * 4;
        tile[r][tx] = in[(size_t)(br + r) * C + bc + tx];
    }
    __syncthreads();
    int c = tid >> 3, rc = (tid & 7) * 8;
#pragma unroll
    for (int p = 0; p < 2; ++p) {
        int cc = c + p * 32;
        bf16x8 o;
#pragma unroll
        for (int e = 0; e < 8; ++e) o[e] = f2br(tile[rc + e][cc]);
        *(bf16x8*)(outp + (size_t)(bc + cc) * R + br + rc) = o;
    }
}

// ---------------------------------------------------------------------------
__device__ __forceinline__ void gload_lds16(const bf16* g, bf16* l)
{
    __builtin_amdgcn_global_load_lds(
        (const __attribute__((address_space(1))) unsigned int*)g,
        (__attribute__((address_space(3))) unsigned int*)l,
        16, 0, 0);
}

#define BAR() asm volatile("s_barrier" ::: "memory")
#define VMCNT0() asm volatile("s_waitcnt vmcnt(0)" ::: "memory")

// ---------------------------------------------------------------------------
// gemm_2ph body (champion): BM_ x BN_ tile, BK=64, 4 waves (2Mx2N),
// double-buffered LDS, vmcnt(0)+barrier per tile (>=2 blocks/CU co-residency
// hides the drain), 16B-chunk XOR swizzle both sides, chunked XCD swizzle.
// MODE 0: standard.  MODE 1: B-only split.  MODE 2: +Hh/Ht epilogue.
// ---------------------------------------------------------------------------
template <int BM_, int BN_, bool RELU, bool OUT_BF16, bool ADD_BIAS, int MODE>
__device__ __forceinline__ void gemm_2ph_body(
    const bf16* __restrict__ A, const bf16* __restrict__ BT,
    const float* __restrict__ bias, const float* __restrict__ hh,
    void* __restrict__ Cout,
    int lda, int ldb, int NT, int nbn, int nper, int ldc, int mrows,
    int bid, int nwg)
{
    constexpr int MFR = BM_ / 32;
    constexpr int NF  = BN_ / 32;
    constexpr int AELEMS = BM_ * 64;
    constexpr int TILE_E = (BM_ + BN_) * 64;
    __shared__ __align__(16) bf16 lds[2][TILE_E];

    const int cpx = nwg >> 3;
    const int wg = (bid & 7) * cpx + (bid >> 3);

    const int s   = wg / nper;
    const int rem = wg - s * nper;
    const int bm  = rem / nbn;
    const int bn  = rem - bm * nbn;
    const int row0 = bm * BM_;
    const int col0 = bn * BN_;

    const bf16* As = A  + (MODE == 1 ? (size_t)0 : (size_t)s * NT * 64);
    const bf16* Bs = BT + (size_t)s * NT * 64;

    const int tid = threadIdx.x;
    const int w = tid >> 6, l = tid & 63;
    const int wm = w >> 1;
    const int wn = w & 1;

    const int lr  = l >> 3;
    const int lch = (l & 7) ^ lr;
    const int l15 = l & 15;
    const int sw0 = (((l >> 4)    ) ^ (l & 7)) * 16;
    const int sw1 = (((l >> 4) + 4) ^ (l & 7)) * 16;

    auto stage = [&](int ts, int sb) {
        const bf16* ga = As + (size_t)(row0 + w * (BM_ / 4) + lr) * lda + ts * 64 + lch * 8;
        bf16* da = &lds[sb][(w * (BM_ / 4)) * 64];
#pragma unroll
        for (int j = 0; j < MFR; ++j)
            gload_lds16(ga + (size_t)(j * 8) * lda, da + j * 512);
        const bf16* gb = Bs + (size_t)(col0 + w * (BN_ / 4) + lr) * ldb + ts * 64 + lch * 8;
        bf16* db = &lds[sb][AELEMS + (w * (BN_ / 4)) * 64];
#pragma unroll
        for (int j = 0; j < NF; ++j)
            gload_lds16(gb + (size_t)(j * 8) * ldb, db + j * 512);
    };

    f32x4 acc[MFR][NF] = {};

    stage(0, 0);
    VMCNT0();
    BAR();

    for (int t = 0; t < NT; ++t) {
        const int sb = t & 1;
        if (t + 1 < NT) stage(t + 1, sb ^ 1);
        const char* Ab = (const char*)&lds[sb][0];
        const char* Bb = (const char*)&lds[sb][AELEMS];
        bf16x8 af[MFR][2], bfr[NF][2];
#pragma unroll
        for (int m = 0; m < MFR; ++m) {
            const char* p = Ab + (wm * (BM_ / 2) + m * 16 + l15) * 128;
            af[m][0] = *(const bf16x8*)(p + sw0);
            af[m][1] = *(const bf16x8*)(p + sw1);
        }
#pragma unroll
        for (int n = 0; n < NF; ++n) {
            const char* p = Bb + (wn * (BN_ / 2) + n * 16 + l15) * 128;
            bfr[n][0] = *(const bf16x8*)(p + sw0);
            bfr[n][1] = *(const bf16x8*)(p + sw1);
        }
#pragma unroll
        for (int m = 0; m < MFR; ++m)
#pragma unroll
            for (int n = 0; n < NF; ++n)
#pragma unroll
                for (int kk = 0; kk < 2; ++kk)
                    acc[m][n] = __builtin_amdgcn_mfma_f32_16x16x32_bf16(
                        af[m][kk], bfr[n][kk], acc[m][n], 0, 0, 0);
        VMCNT0();
        BAR();
    }

    const int crow = (l >> 4) * 4;
    char* outBase = (char*)Cout + (size_t)s * mrows * ldc * (OUT_BF16 ? 2 : 4);
    const float* htp = (MODE == 2) ? hh + (size_t)128 * FFN : nullptr;
#pragma unroll
    for (int m = 0; m < MFR; ++m) {
        int row = row0 + wm * (BM_ / 2) + m * 16 + crow;
#pragma unroll
        for (int n = 0; n < NF; ++n) {
            int col = col0 + wn * (BN_ / 2) + n * 16 + l15;
            float bv = ADD_BIAS ? bias[col] : 0.f;
#pragma unroll
            for (int q = 0; q < 4; ++q) {
                int r = row + q;
                float v = acc[m][n][q] + bv;
                if (MODE == 2) {
                    int bq = r >> 10;
                    int ih = bq * 32 + ((r >> 5) & 31);
                    int jt = bq * 32 + (r & 31);
                    v += hh[(size_t)ih * FFN + col] + htp[(size_t)jt * FFN + col];
                }
                if (RELU) v = fmaxf(v, 0.f);
                size_t idx = (size_t)r * ldc + col;
                if (OUT_BF16)
                    ((bf16*)outBase)[idx] = __float2bfloat16(v);
                else
                    ((float*)outBase)[idx] = v;
            }
        }
    }
}

// ---------------------------------------------------------------------------
// fused_mid (D2): blocks [0,48): gemm1a (Hh/Ht = candB @ W1T k-halves).
//   blocks [48, 48+1024): build_ctx, ONE WAVE per pair (4 pairs/block).
//   Queries: L<4 direct; L<16 q=4 x4; L<64 q=16 x4; else q=64 wave-uniform
//   loop (ceil(L/64) <= 16 lookups, no divergence: pair is wave-uniform).
// Both depend only on D1.
// ---------------------------------------------------------------------------
__global__ __launch_bounds__(256, 2) void fused_mid(
    const bf16* __restrict__ candB, const bf16* __restrict__ W1T,
    float* __restrict__ HhHt,
    const float* __restrict__ cand, const float* __restrict__ tok,
    const int* __restrict__ ids, const bf16* __restrict__ tbl,
    bf16* __restrict__ ctxB)
{
    if (blockIdx.x < 48) {
        gemm_2ph_body<128, 96, false, false, false, 1>(
            candB, W1T, nullptr, nullptr, HhHt,
            HH, K1, /*NT=*/8, /*nbn=*/24, /*nper=*/24, FFN, /*mrows=*/128,
            blockIdx.x, 48);
        return;
    }
    int w = threadIdx.x >> 6, l = threadIdx.x & 63;
    int pair = (blockIdx.x - 48) * 4 + w;
    int b = pair >> 10;
    int i = (pair >> 5) & 31;
    int j = pair & 31;
    int h0 = l * 8;

    int si = ids[((b * KK + i) << 1)];
    int ei = ids[((b * KK + i) << 1) + 1];
    int sj = ids[((b * KK + j) << 1)];
    int ej = ids[((b * KK + j) << 1) + 1];
    int me = min(ei, ej);
    int ms = max(si, sj);

    float m[8];
    bf16x8 o;
    if (me < ms) {
        int L = ms - me;
#pragma unroll
        for (int e = 0; e < 8; ++e) m[e] = -INFINITY;
        if (L < 4) {
            const float* tb = tok + (size_t)b * SS * HH + h0;
            for (int tt = me; tt < ms; ++tt) {
                float4 v0 = *(const float4*)(tb + (size_t)tt * HH);
                float4 v1 = *(const float4*)(tb + (size_t)tt * HH + 4);
                m[0] = fmaxf(m[0], v0.x); m[1] = fmaxf(m[1], v0.y);
                m[2] = fmaxf(m[2], v0.z); m[3] = fmaxf(m[3], v0.w);
                m[4] = fmaxf(m[4], v1.x); m[5] = fmaxf(m[5], v1.y);
                m[6] = fmaxf(m[6], v1.z); m[7] = fmaxf(m[7], v1.w);
            }
        } else if (L < 64) {
            int lvl = (L < 16) ? 0 : 1;
            int q = (L < 16) ? 4 : 16;
            const bf16* base = tbl + (size_t)lvl * TBL_LVL_STRIDE
                               + (size_t)b * SS * HH + h0;
#pragma unroll
            for (int jj = 0; jj < 4; ++jj) {
                int p = min(me + jj * q, ms - q);
                bf16x8 v = *(const bf16x8*)(base + (size_t)p * HH);
#pragma unroll
                for (int e = 0; e < 8; ++e)
                    m[e] = fmaxf(m[e], b2fr(v[e]));
            }
        } else {                // q=64 wave-uniform loop
            const bf16* base = tbl + (size_t)2 * TBL_LVL_STRIDE
                               + (size_t)b * SS * HH + h0;
            int p = me;
            while (p + 64 < ms) {
                bf16x8 v = *(const bf16x8*)(base + (size_t)p * HH);
#pragma unroll
                for (int e = 0; e < 8; ++e)
                    m[e] = fmaxf(m[e], b2fr(v[e]));
                p += 64;
            }
            bf16x8 v = *(const bf16x8*)(base + (size_t)(ms - 64) * HH);
#pragma unroll
            for (int e = 0; e < 8; ++e)
                m[e] = fmaxf(m[e], b2fr(v[e]));
        }
#pragma unroll
        for (int e = 0; e < 8; ++e) o[e] = f2br(m[e]);
    } else {
        const float* hp = cand + ((size_t)b * KK + i) * HH + h0;
        float4 v0 = *(const float4*)hp;
        float4 v1 = *(const float4*)(hp + 4);
        o[0] = f2br(v0.x); o[1] = f2br(v0.y); o[2] = f2br(v0.z); o[3] = f2br(v0.w);
        o[4] = f2br(v1.x); o[5] = f2br(v1.y); o[6] = f2br(v1.z); o[7] = f2br(v1.w);
    }
    *(bf16x8*)(ctxB + (size_t)pair * HH + h0) = o;
}

// ---------------------------------------------------------------------------
template <int BM_, int BN_, bool RELU, bool OUT_BF16, bool ADD_BIAS, int MODE>
__global__ __launch_bounds__(256, 2) void gemm_2ph(
    const bf16* __restrict__ A, const bf16* __restrict__ BT,
    const float* __restrict__ bias, const float* __restrict__ hh,
    void* __restrict__ Cout,
    int lda, int ldb, int NT, int nbn, int nper, int ldc, int mrows)
{
    gemm_2ph_body<BM_, BN_, RELU, OUT_BF16, ADD_BIAS, MODE>(
        A, BT, bias, hh, Cout, lda, ldb, NT, nbn, nper, ldc, mrows,
        blockIdx.x, gridDim.x);
}

// ---------------------------------------------------------------------------
extern "C" void kernel_launch(void* const* d_in, const int* in_sizes, int n_in,
                              void* d_out, int out_size, void* d_ws, size_t ws_size,
                              hipStream_t stream)
{
    const float* cand = (const float*)d_in[0];
    const float* tok  = (const float*)d_in[1];
    const float* W1   = (const float*)d_in[2];
    const float* b1   = (const float*)d_in[3];
    const float* W2   = (const float*)d_in[4];
    const float* b2   = (const float*)d_in[5];
    const int*   ids  = (const int*)d_in[6];
    float* out = (float*)d_out;

    char* ws = (char*)d_ws;
    const size_t ctx_sz  = (size_t)M_PAIRS * HH * 2;        //  4,194,304
    const size_t cnd_sz  = (size_t)BB * KK * HH * 2;        //    131,072
    const size_t w1t_sz  = (size_t)FFN * K1 * 2;            //  7,077,888
    const size_t w2t_sz  = (size_t)HH * FFN * 2;            //  2,359,296
    const size_t hht_sz  = (size_t)2 * 128 * FFN * 4;       //  2,359,296
    bf16*  ctxB  = (bf16*)ws;
    bf16*  candB = (bf16*)(ws + ctx_sz);
    bf16*  W1T   = (bf16*)(ws + ctx_sz + cnd_sz);
    bf16*  W2T   = (bf16*)(ws + ctx_sz + cnd_sz + w1t_sz);
    float* HhHt  = (float*)(ws + ctx_sz + cnd_sz + w1t_sz + w2t_sz);
    char* regionX = ws + ctx_sz + cnd_sz + w1t_sz + w2t_sz + hht_sz;
    bf16* tbl = (bf16*)regionX;   // 12 MB (3 levels), dead after build_ctx
    bf16* hid = (bf16*)regionX;   // 18.9 MB, written by gemm1c afterwards

    // D1) all-level tables (q=4,16,64) + 64x64 transposes + cand cast
    fused_pre<<<PRE_TOTAL, 256, 0, stream>>>(
        W1, W1T, W2, W2T, cand, candB, tok,
        tbl + 0 * TBL_LVL_STRIDE, tbl + 1 * TBL_LVL_STRIDE,
        tbl + 2 * TBL_LVL_STRIDE);

    // D2) gemm1a (Hh/Ht) + build_ctx (both depend only on D1)
    fused_mid<<<48 + M_PAIRS / 4, 256, 0, stream>>>(
        candB, W1T, HhHt, cand, tok, ids, tbl, ctxB);

    // D3) gemm1c: hid = relu(ctxB @ W1c^T + Hh[i] + Ht[j] + b1).
    //     64x96 tiles, grid 64x24 = 1536 = exactly 6 blocks/CU.
    gemm_2ph<64, 96, true, true, true, 2><<<1536, 256, 0, stream>>>(
        ctxB, W1T + 1024, b1, HhHt, hid,
        HH, K1, /*NT=*/8, /*nbn=*/24, /*nper=*/1536, FFN, /*mrows=*/0);

    // D4) out = hid @ W2 + b2 -> f32. 64x64 tiles, grid 64x8 = 512 = 2/CU.
    gemm_2ph<64, 64, false, false, true, 0><<<512, 256, 0, stream>>>(
        hid, W2T, b2, nullptr, out,
        FFN, FFN, /*NT=*/36, /*nbn=*/8, /*nper=*/512, HH, /*mrows=*/0);
}